// Round 7
// baseline (191.168 us; speedup 1.0000x reference)
//
#include <hip/hip_runtime.h>
#include <cstdint>
#include <cstddef>

#define NN 16   // neighbors
#define DI 32
#define DO 64

typedef short bf16x8 __attribute__((ext_vector_type(8)));
typedef short bf16x4 __attribute__((ext_vector_type(4)));
typedef float f32x4 __attribute__((ext_vector_type(4)));

// K=16 bf16 MFMA: B-operand layout (k=quad*4+j, col) == phase-A C-layout, so the
// softmax output feeds phase B with zero cross-lane traffic.
#if defined(__has_builtin)
#  if __has_builtin(__builtin_amdgcn_mfma_f32_16x16x16_bf16)
#    define MFMA_K16(a, b, c) __builtin_amdgcn_mfma_f32_16x16x16_bf16(a, b, c, 0, 0, 0)
#    define HAVE_K16 1
#  elif __has_builtin(__builtin_amdgcn_mfma_f32_16x16x16bf16_1k)
#    define MFMA_K16(a, b, c) __builtin_amdgcn_mfma_f32_16x16x16bf16_1k(a, b, c, 0, 0, 0)
#    define HAVE_K16 1
#  endif
#endif

// ---------- tables ----------
__device__ __constant__ int c_INV[12][6] = {
  {0,1,2,3,4,5},{0,5,4,3,2,1},{4,3,0,5,2,1},{1,2,4,3,5,0},
  {3,5,2,0,4,1},{1,4,3,5,0,2},{4,0,3,1,2,5},{1,0,2,4,3,5},
  {4,1,2,5,0,3},{3,1,4,0,2,5},{2,1,4,5,3,0},{4,5,0,3,1,2}};
__device__ __constant__ int c_ROLL[5][6] = {
  {0,1,2,3,4,5},{0,2,3,4,5,1},{0,3,4,5,1,2},{0,4,5,1,2,3},{0,5,1,2,3,4}};
__device__ __constant__ float c_VS[12][3] = {
  {0.f, 0.5257311121f, 0.8506508084f},
  {0.f, 0.5257311121f, -0.8506508084f},
  {0.f, -0.5257311121f, 0.8506508084f},
  {0.f, -0.5257311121f, -0.8506508084f},
  {0.5257311121f, 0.8506508084f, 0.f},
  {0.5257311121f, -0.8506508084f, 0.f},
  {-0.5257311121f, 0.8506508084f, 0.f},
  {-0.5257311121f, -0.8506508084f, 0.f},
  {0.8506508084f, 0.f, 0.5257311121f},
  {0.8506508084f, 0.f, -0.5257311121f},
  {-0.8506508084f, 0.f, 0.5257311121f},
  {-0.8506508084f, 0.f, -0.5257311121f}};
__device__ __constant__ int c_C2V[6][2] = {{0,1},{6,7},{2,11},{4,9},{5,8},{3,10}};

// ---------- helpers ----------
__device__ inline unsigned short f2bf(float f) {
  unsigned int u = __float_as_uint(f);
  unsigned int r = (u + 0x7fffu + ((u >> 16) & 1u)) >> 16;   // RNE
  return (unsigned short)r;
}
__device__ inline float bf2f(unsigned short h) {
  return __uint_as_float(((unsigned int)h) << 16);
}
__device__ inline unsigned int pack2(float a, float b) {
  return (unsigned int)f2bf(a) | ((unsigned int)f2bf(b) << 16);
}

__device__ inline float sym13(const float* __restrict__ w, int k, int j) {
  if (k == 0)  return w[j == 0 ? 0 : 1];
  if (k == 1)  return w[j == 0 ? 2 : 3];
  if (k == 12) return w[j == 0 ? 4 : 5];
  int a = (k - 2) / 5, rr = (k - 2) % 5;
  return w[6 + a * 6 + c_ROLL[rr][j]];
}

// ---------- k0: weight expansion (k-major bf16) + fmT + passthrough ----------
__global__ __launch_bounds__(256) void k0_expand(
    const float* __restrict__ W, const float* __restrict__ Wdir,
    const float* __restrict__ fm,
    unsigned short* __restrict__ A_bf,
    unsigned short* __restrict__ W2k,
    unsigned short* __restrict__ Wck,
    unsigned short* __restrict__ fmTbf,   // [V][192] bf16
    float* __restrict__ out_fm, int V) {
  int idx = blockIdx.x * 256 + threadIdx.x;
  if (idx < 221184) {
    int row = idx / 192, ci = idx % 192;
    int h = row / 144, k = (row / 12) % 12, r = row % 12;
    int c = ci / 6, i = ci % 6;
    int rt = row >> 4, rl = row & 15;
    int ks = ci >> 5, q = (ci >> 3) & 3, j = ci & 7;
    A_bf[(((rt * 6 + ks) * 4 + q) * 16 + rl) * 8 + j] =
        f2bf(0.5f * sym13(&Wdir[(h * 32 + c) * 18], k, c_INV[r][i]));
  } else if (idx < 1990656) {
    int e = idx - 221184;
    int kr = e / 12288, rem = e % 12288;
    int k = kr / 12, r = kr % 12, d = rem / 192, ci = rem % 192;
    int c = ci / 6, i = ci % 6;
    int ks = ci >> 5, q = (ci >> 3) & 3, j = ci & 7;
    W2k[kr * 12288 + ((ks * 4 + q) * 64 + d) * 8 + j] =
        f2bf(sym13(&W[(d * 32 + c) * 18], k, c_INV[r][i]));
  } else if (idx < 2138112) {
    int e = idx - 1990656;
    int r = e / 12288, rem = e % 12288, d = rem / 192, ci = rem % 192;
    int c = ci / 6, i = ci % 6;
    int ks = ci >> 5, q = (ci >> 3) & 3, j = ci & 7;
    Wck[r * 12288 + ((ks * 4 + q) * 64 + d) * 8 + j] =
        f2bf(sym13(&W[(d * 32 + c) * 18], 12, c_INV[r][i]));
  } else {
    int e = idx - 2138112;
    if (e < 192 * V) {
      int p = e / 192, ci = e % 192, c = ci / 6, i = ci % 6;
      float v = fm[(c * V + p) * 6 + i];
      fmTbf[e] = f2bf(v);
      out_fm[(c * V + p) * 6 + i] = v;
    }
  }
}

// ---------- k1: directions + de6 + W_dim -> cross_n [p][n][ci] + crossT_g [p][ci][n] ----------
__global__ __launch_bounds__(256) void k1_cross(
    const int* __restrict__ nbi, const float* __restrict__ verts,
    const float* __restrict__ fm, const float* __restrict__ Wdim,
    unsigned short* __restrict__ cross_n,
    unsigned short* __restrict__ crossT_g, int V) {
  __shared__ float in_s[NN * 33 * 6];
  __shared__ float wd_s[33 * 32];
  __shared__ unsigned int cross_u[1536];   // [n][ci2] packed bf16 pairs
  __shared__ int nb_s[NN];
  int p = blockIdx.x, t = threadIdx.x;
  if (t < NN) nb_s[t] = nbi[p * NN + t];
  for (int idx = t; idx < 1056; idx += 256) wd_s[idx] = Wdim[idx];
  __syncthreads();
  // vectorized gather: 3 x float2 per (n,c) row (24B-aligned source)
  for (int idx = t; idx < NN * 32; idx += 256) {
    int n = idx >> 5, c = idx & 31;
    const float* src = fm + ((size_t)c * V + nb_s[n]) * 6;
    float2 a  = *(const float2*)(src + 0);
    float2 b  = *(const float2*)(src + 2);
    float2 cd = *(const float2*)(src + 4);
    float* d = &in_s[(n * 33 + c) * 6];
    d[0] = a.x; d[1] = a.y; d[2] = b.x; d[3] = b.y; d[4] = cd.x; d[5] = cd.y;
  }
  if (t < NN) {
    int n = t, nb = nb_s[n];
    float px = verts[p * 3 + 0], py = verts[p * 3 + 1], pz = verts[p * 3 + 2];
    float dx = verts[nb * 3 + 0] - px, dy = verts[nb * 3 + 1] - py, dz = verts[nb * 3 + 2] - pz;
    float L = sqrtf(dx * dx + dy * dy + dz * dz);
    float inv = 1.0f / fmaxf(L, 1e-12f);
    dx *= inv; dy *= inv; dz *= inv;
    float de[12];
    #pragma unroll
    for (int v = 0; v < 12; ++v)
      de[v] = c_VS[v][0] * dx + c_VS[v][1] * dy + c_VS[v][2] * dz;
    #pragma unroll
    for (int j = 0; j < 6; ++j)
      in_s[(n * 33 + 32) * 6 + j] = fmaxf(de[c_C2V[j][0]], de[c_C2V[j][1]]);
  }
  __syncthreads();
  for (int idx = t; idx < 1536; idx += 256) {
    int n = idx / 96, cp2 = idx % 96;
    int ci0 = cp2 * 2, ci1 = ci0 + 1;
    int o0 = ci0 / 6, i0 = ci0 % 6;
    int o1 = ci1 / 6, i1 = ci1 % 6;
    float s0 = 0.f, s1 = 0.f;
    #pragma unroll
    for (int c = 0; c <= 32; ++c) {
      float f0 = in_s[(n * 33 + c) * 6 + i0];
      float f1 = in_s[(n * 33 + c) * 6 + i1];
      s0 = fmaf(wd_s[c * 32 + o0], f0, s0);
      s1 = fmaf(wd_s[c * 32 + o1], f1, s1);
    }
    cross_u[idx] = (unsigned int)f2bf(s0) | ((unsigned int)f2bf(s1) << 16);
  }
  __syncthreads();
  {
    const uint4* src = (const uint4*)cross_u;
    uint4* d1 = (uint4*)(cross_n + (size_t)p * 3072);
    for (int idx = t; idx < 384; idx += 256) d1[idx] = src[idx];
  }
  {
    unsigned int* d2 = (unsigned int*)(crossT_g + (size_t)p * 3072);
    for (int idx = t; idx < 1536; idx += 256) {
      int np = idx / 192, ci = idx % 192;
      unsigned int u0 = cross_u[(2 * np) * 96 + (ci >> 1)];
      unsigned int u1 = cross_u[(2 * np + 1) * 96 + (ci >> 1)];
      unsigned int h0 = (ci & 1) ? (u0 >> 16) : (u0 & 0xffffu);
      unsigned int h1 = (ci & 1) ? (u1 & 0xffff0000u) : (u1 << 16);
      d2[ci * 8 + np] = h0 | h1;
    }
  }
}

// ---------- k2: MFMA act GEMM + row-softmax + K16-MFMA nfm (no cross-lane act move) ----------
__global__ __launch_bounds__(256, 4) void k2_main(
    const unsigned short* __restrict__ A_bf,      // k-major
    const unsigned short* __restrict__ cross_n,   // [p][n][ci]
    const unsigned short* __restrict__ crossT_g,  // [p][ci][n]
    unsigned short* __restrict__ nfm, int V) {
  __shared__ __align__(16) unsigned short crossT[2][192][40];  // [p][ci][n], n 16..31 zero
  int t = threadIdx.x;
  int w = t >> 6, lane = t & 63;
  int quad = lane >> 4, col = lane & 15;
  int p0 = blockIdx.x * 2;

  bf16x8 Afr[2][6];
  #pragma unroll
  for (int p = 0; p < 2; ++p)
    #pragma unroll
    for (int ks = 0; ks < 6; ++ks)
      Afr[p][ks] = *(const bf16x8*)(cross_n + (size_t)(p0 + p) * 3072 + col * 192 + ks * 32 + quad * 8);

  for (int idx = t; idx < 768; idx += 256) {
    int p = idx / 384, rem = idx % 384, ci = rem >> 1, half = rem & 1;
    *(uint4*)&crossT[p][ci][half * 8] =
        *(const uint4*)(crossT_g + (size_t)(p0 + p) * 3072 + ci * 16 + half * 8);
  }
  for (int idx = t; idx < 768; idx += 256) {
    int p = idx / 384, rem = idx % 384, ci = rem >> 1, half = rem & 1;
    *(uint4*)&crossT[p][ci][16 + half * 8] = make_uint4(0u, 0u, 0u, 0u);
  }
  __syncthreads();   // the only barrier

#ifndef HAVE_K16
  int s0l = quad * 32 + col;
  int s1l = s0l + 16;
#endif

  for (int rt = w; rt < 72; rt += 4) {
    int h = rt / 9;
    // ---- phase A: actT[n][kr] ----
    f32x4 acc[2];
    acc[0] = (f32x4){0.f, 0.f, 0.f, 0.f};
    acc[1] = (f32x4){0.f, 0.f, 0.f, 0.f};
    const unsigned short* Abase = A_bf + rt * 3072 + quad * 128 + col * 8;
    #pragma unroll
    for (int ks = 0; ks < 6; ++ks) {
      bf16x8 wf = *(const bf16x8*)(Abase + ks * 512);
      acc[0] = __builtin_amdgcn_mfma_f32_16x16x32_bf16(Afr[0][ks], wf, acc[0], 0, 0, 0);
      acc[1] = __builtin_amdgcn_mfma_f32_16x16x32_bf16(Afr[1][ks], wf, acc[1], 0, 0, 0);
    }
    int row0 = h * 24 + col;
    int row1 = min(h * 24 + 16 + col, 191);
    #pragma unroll
    for (int p = 0; p < 2; ++p) {
      // ---- softmax over n = rows ----
      float v0 = acc[p][0], v1 = acc[p][1], v2 = acc[p][2], v3 = acc[p][3];
      float mx = fmaxf(fmaxf(v0, v1), fmaxf(v2, v3));
      mx = fmaxf(mx, __shfl_xor(mx, 16));
      mx = fmaxf(mx, __shfl_xor(mx, 32));
      float e0 = __expf(v0 - mx), e1 = __expf(v1 - mx);
      float e2 = __expf(v2 - mx), e3 = __expf(v3 - mx);
      float s = (e0 + e1) + (e2 + e3);
      s += __shfl_xor(s, 16);
      s += __shfl_xor(s, 32);
      float inv = __builtin_amdgcn_rcpf(s);
      unsigned int lo = pack2(e0 * inv, e1 * inv);
      unsigned int hi = pack2(e2 * inv, e3 * inv);
      f32x4 o0 = (f32x4){0.f, 0.f, 0.f, 0.f}, o1 = o0;
#ifdef HAVE_K16
      // lane already holds act[n=quad*4+j][kr=col] == B-operand layout for K=16
      union { uint2 u; bf16x4 v; } bcvt;
      bcvt.u = make_uint2(lo, hi);
      bf16x4 a0 = *(const bf16x4*)&crossT[p][row0][quad * 4];
      bf16x4 a1 = *(const bf16x4*)&crossT[p][row1][quad * 4];
      o0 = MFMA_K16(a0, bcvt.v, o0);
      o1 = MFMA_K16(a1, bcvt.v, o1);
#else
      unsigned int b0 = (unsigned int)__shfl((int)lo, s0l);
      unsigned int b1 = (unsigned int)__shfl((int)hi, s0l);
      unsigned int b2 = (unsigned int)__shfl((int)lo, s1l);
      unsigned int b3 = (unsigned int)__shfl((int)hi, s1l);
      bool vq = (quad < 2);
      union { uint4 u; bf16x8 v; } cvt;
      cvt.u = make_uint4(vq ? b0 : 0u, vq ? b1 : 0u, vq ? b2 : 0u, vq ? b3 : 0u);
      bf16x8 a0 = *(const bf16x8*)&crossT[p][row0][quad * 8];
      bf16x8 a1 = *(const bf16x8*)&crossT[p][row1][quad * 8];
      o0 = __builtin_amdgcn_mfma_f32_16x16x32_bf16(a0, cvt.v, o0, 0, 0, 0);
      o1 = __builtin_amdgcn_mfma_f32_16x16x32_bf16(a1, cvt.v, o1, 0, 0, 0);
#endif
      // ---- direct global stores: rowbase = p*27648 + (rt*16+col)*24 ----
      size_t rowbase = (size_t)(p0 + p) * 27648 + (size_t)(rt * 16 + col) * 24;
      uint2 w0;
      w0.x = pack2(o0[0], o0[1]);
      w0.y = pack2(o0[2], o0[3]);
      *(uint2*)(nfm + rowbase + quad * 4) = w0;
      if (quad < 2) {
        uint2 w1;
        w1.x = pack2(o1[0], o1[1]);
        w1.y = pack2(o1[2], o1[3]);
        *(uint2*)(nfm + rowbase + 16 + quad * 4) = w1;
      }
    }
  }
}

// ---------- k3: MFMA feat GEMMs + center + fused c2v max -> out ----------
// grid (V/32, 6), 512 threads = 8 waves: waves 0-3 -> r0=c2v[j][0] (K-split 4),
// waves 4-7 -> r1=c2v[j][1]. LDS reduce, then max, write out directly.
__global__ __launch_bounds__(512) void k3_feat(
    const unsigned short* __restrict__ W2k,
    const unsigned short* __restrict__ Wck,
    const unsigned short* __restrict__ fmTbf,
    const unsigned short* __restrict__ nfm,
    float* __restrict__ out, int V) {
  __shared__ float red[2][3][32][64];   // 49152 B
  int pb = blockIdx.x, j = blockIdx.y;
  int t = threadIdx.x, w = t >> 6, lane = t & 63;
  int rhalf = w >> 2, kw = w & 3;
  int r = c_C2V[j][rhalf];
  int quad = lane >> 4, col = lane & 15;
  int p0 = pb * 32;
  f32x4 acc[4][2];
  #pragma unroll
  for (int m = 0; m < 4; ++m)
    #pragma unroll
    for (int jj = 0; jj < 2; ++jj) acc[m][jj] = (f32x4){0.f, 0.f, 0.f, 0.f};

  int base24[6];
  #pragma unroll
  for (int ks = 0; ks < 6; ++ks) {
    int ci = ks * 32 + quad * 8;
    int hh = ci / 24, oo = ci - hh * 24;
    base24[ks] = hh * 3456 + oo;   // h*144*24 + off
  }

  const unsigned short* Bn0 = nfm + (size_t)(p0 + col) * 27648;
  const unsigned short* Bn1 = nfm + (size_t)(p0 + 16 + col) * 27648;
  const unsigned short* Bc0 = fmTbf + (size_t)(p0 + col) * 192;
  const unsigned short* Bc1 = fmTbf + (size_t)(p0 + 16 + col) * 192;

  int nkb = (kw == 3) ? 4 : 3;
  for (int i = 0; i < nkb; ++i) {
    int kb = kw * 3 + i;   // kw=3,i=3 -> 12 (center)
    const unsigned short* Ab;
    int kr24 = 0;
    if (kb < 12) { Ab = W2k + (size_t)(kb * 12 + r) * 12288; kr24 = (kb * 12 + r) * 24; }
    else         { Ab = Wck + (size_t)r * 12288; }
    const unsigned short* Albase = Ab + quad * 512 + col * 8;
    #pragma unroll
    for (int ks = 0; ks < 6; ++ks) {
      bf16x8 b0, b1;
      if (kb < 12) {
        b0 = *(const bf16x8*)(Bn0 + base24[ks] + kr24);
        b1 = *(const bf16x8*)(Bn1 + base24[ks] + kr24);
      } else {
        int ko = ks * 32 + quad * 8;
        b0 = *(const bf16x8*)(Bc0 + ko);
        b1 = *(const bf16x8*)(Bc1 + ko);
      }
      #pragma unroll
      for (int m = 0; m < 4; ++m) {
        bf16x8 a = *(const bf16x8*)(Albase + ks * 2048 + m * 128);
        acc[m][0] = __builtin_amdgcn_mfma_f32_16x16x32_bf16(a, b0, acc[m][0], 0, 0, 0);
        acc[m][1] = __builtin_amdgcn_mfma_f32_16x16x32_bf16(a, b1, acc[m][1], 0, 0, 0);
      }
    }
  }
  // K-split partial dump (kw>0)
  if (kw > 0) {
    #pragma unroll
    for (int m = 0; m < 4; ++m)
      #pragma unroll
      for (int jj = 0; jj < 2; ++jj)
        #pragma unroll
        for (int rr = 0; rr < 4; ++rr)
          red[rhalf][kw - 1][m * 8 + jj * 4 + rr][lane] = acc[m][jj][rr];
  }
  __syncthreads();
  if (kw == 0) {
    #pragma unroll
    for (int m = 0; m < 4; ++m)
      #pragma unroll
      for (int jj = 0; jj < 2; ++jj)
        #pragma unroll
        for (int rr = 0; rr < 4; ++rr) {
          int ri = m * 8 + jj * 4 + rr;
          acc[m][jj][rr] += red[rhalf][0][ri][lane] + red[rhalf][1][ri][lane] + red[rhalf][2][ri][lane];
        }
  }
  if (w == 4) {
    #pragma unroll
    for (int m = 0; m < 4; ++m)
      #pragma unroll
      for (int jj = 0; jj < 2; ++jj)
        #pragma unroll
        for (int rr = 0; rr < 4; ++rr)
          red[1][0][m * 8 + jj * 4 + rr][lane] = acc[m][jj][rr];
  }
  __syncthreads();
  if (w == 0) {
    #pragma unroll
    for (int m = 0; m < 4; ++m)
      #pragma unroll
      for (int jj = 0; jj < 2; ++jj)
        #pragma unroll
        for (int rr = 0; rr < 4; ++rr) {
          float v = fmaxf(acc[m][jj][rr], red[1][0][m * 8 + jj * 4 + rr][lane]);
          int d = m * 16 + quad * 4 + rr;
          int p = p0 + jj * 16 + col;
          out[((size_t)d * V + p) * 6 + j] = v;
        }
  }
}

// ---------- host ----------
extern "C" void kernel_launch(void* const* d_in, const int* in_sizes, int n_in,
                              void* d_out, int out_size, void* d_ws, size_t ws_size,
                              hipStream_t stream) {
  const int* nbi = (const int*)d_in[0];
  const float* verts = (const float*)d_in[1];
  const float* fm = (const float*)d_in[2];
  const float* Wdim = (const float*)d_in[3];
  const float* W = (const float*)d_in[4];
  const float* Wdir = (const float*)d_in[5];
  float* out = (float*)d_out;
  float* ws = (float*)d_ws;
  int V = in_sizes[0] / NN;   // 2048

  unsigned short* A_bf  = (unsigned short*)ws;             // 221184 ush
  unsigned short* W2k   = (unsigned short*)(ws + 110592);  // 1769472 ush
  unsigned short* Wck   = (unsigned short*)(ws + 995328);  // 147456 ush
  unsigned short* fmTbf = (unsigned short*)(ws + 1069056); // 192*V ush
  size_t o = 1069056 + (size_t)96 * V;
  unsigned short* cross_n = (unsigned short*)(ws + o);     // 3072*V ush [p][n][ci]
  o += (size_t)1536 * V;
  unsigned short* crossT_g = (unsigned short*)(ws + o);    // 3072*V ush [p][ci][n]
  o += (size_t)1536 * V;
  unsigned short* nfm = (unsigned short*)(ws + o);         // 27648*V ush [p][h][144][24]

  int n0 = 2138112 + 192 * V;
  k0_expand<<<(n0 + 255) / 256, 256, 0, stream>>>(W, Wdir, fm, A_bf, W2k, Wck, fmTbf,
                                                  out + (size_t)DO * V * 6, V);
  k1_cross<<<V, 256, 0, stream>>>(nbi, verts, fm, Wdim, cross_n, crossT_g, V);
  k2_main<<<V / 2, 256, 0, stream>>>(A_bf, cross_n, crossT_g, nfm, V);
  k3_feat<<<dim3(V / 32, 6), 512, 0, stream>>>(W2k, Wck, fmTbf, nfm, out, V);
}

// Round 8
// 180.151 us; speedup vs baseline: 1.0612x; 1.0612x over previous
//
#include <hip/hip_runtime.h>
#include <cstdint>
#include <cstddef>

#define NN 16   // neighbors
#define DI 32
#define DO 64

typedef short bf16x8 __attribute__((ext_vector_type(8)));
typedef short bf16x4 __attribute__((ext_vector_type(4)));
typedef float f32x4 __attribute__((ext_vector_type(4)));

// K=16 bf16 MFMA: B-operand layout (k=quad*4+j, col) == phase-A C-layout, so the
// softmax output feeds phase B with zero cross-lane traffic.
#if defined(__has_builtin)
#  if __has_builtin(__builtin_amdgcn_mfma_f32_16x16x16_bf16)
#    define MFMA_K16(a, b, c) __builtin_amdgcn_mfma_f32_16x16x16_bf16(a, b, c, 0, 0, 0)
#    define HAVE_K16 1
#  elif __has_builtin(__builtin_amdgcn_mfma_f32_16x16x16bf16_1k)
#    define MFMA_K16(a, b, c) __builtin_amdgcn_mfma_f32_16x16x16bf16_1k(a, b, c, 0, 0, 0)
#    define HAVE_K16 1
#  endif
#endif

// ---------- tables ----------
__device__ __constant__ int c_INV[12][6] = {
  {0,1,2,3,4,5},{0,5,4,3,2,1},{4,3,0,5,2,1},{1,2,4,3,5,0},
  {3,5,2,0,4,1},{1,4,3,5,0,2},{4,0,3,1,2,5},{1,0,2,4,3,5},
  {4,1,2,5,0,3},{3,1,4,0,2,5},{2,1,4,5,3,0},{4,5,0,3,1,2}};
__device__ __constant__ int c_ROLL[5][6] = {
  {0,1,2,3,4,5},{0,2,3,4,5,1},{0,3,4,5,1,2},{0,4,5,1,2,3},{0,5,1,2,3,4}};
__device__ __constant__ float c_VS[12][3] = {
  {0.f, 0.5257311121f, 0.8506508084f},
  {0.f, 0.5257311121f, -0.8506508084f},
  {0.f, -0.5257311121f, 0.8506508084f},
  {0.f, -0.5257311121f, -0.8506508084f},
  {0.5257311121f, 0.8506508084f, 0.f},
  {0.5257311121f, -0.8506508084f, 0.f},
  {-0.5257311121f, 0.8506508084f, 0.f},
  {-0.5257311121f, -0.8506508084f, 0.f},
  {0.8506508084f, 0.f, 0.5257311121f},
  {0.8506508084f, 0.f, -0.5257311121f},
  {-0.8506508084f, 0.f, 0.5257311121f},
  {-0.8506508084f, 0.f, -0.5257311121f}};
__device__ __constant__ int c_C2V[6][2] = {{0,1},{6,7},{2,11},{4,9},{5,8},{3,10}};

// ---------- helpers ----------
__device__ inline unsigned short f2bf(float f) {
  unsigned int u = __float_as_uint(f);
  unsigned int r = (u + 0x7fffu + ((u >> 16) & 1u)) >> 16;   // RNE
  return (unsigned short)r;
}
__device__ inline float bf2f(unsigned short h) {
  return __uint_as_float(((unsigned int)h) << 16);
}
__device__ inline unsigned int pack2(float a, float b) {
  return (unsigned int)f2bf(a) | ((unsigned int)f2bf(b) << 16);
}

__device__ inline float sym13(const float* __restrict__ w, int k, int j) {
  if (k == 0)  return w[j == 0 ? 0 : 1];
  if (k == 1)  return w[j == 0 ? 2 : 3];
  if (k == 12) return w[j == 0 ? 4 : 5];
  int a = (k - 2) / 5, rr = (k - 2) % 5;
  return w[6 + a * 6 + c_ROLL[rr][j]];
}

// ---------- k0: weight expansion (k-major bf16) + fmT + passthrough ----------
__global__ __launch_bounds__(256) void k0_expand(
    const float* __restrict__ W, const float* __restrict__ Wdir,
    const float* __restrict__ fm,
    unsigned short* __restrict__ A_bf,
    unsigned short* __restrict__ W2k,
    unsigned short* __restrict__ Wck,
    unsigned short* __restrict__ fmTbf,   // [V][192] bf16
    float* __restrict__ out_fm, int V) {
  int idx = blockIdx.x * 256 + threadIdx.x;
  if (idx < 221184) {
    int row = idx / 192, ci = idx % 192;
    int h = row / 144, k = (row / 12) % 12, r = row % 12;
    int c = ci / 6, i = ci % 6;
    int rt = row >> 4, rl = row & 15;
    int ks = ci >> 5, q = (ci >> 3) & 3, j = ci & 7;
    A_bf[(((rt * 6 + ks) * 4 + q) * 16 + rl) * 8 + j] =
        f2bf(0.5f * sym13(&Wdir[(h * 32 + c) * 18], k, c_INV[r][i]));
  } else if (idx < 1990656) {
    int e = idx - 221184;
    int kr = e / 12288, rem = e % 12288;
    int k = kr / 12, r = kr % 12, d = rem / 192, ci = rem % 192;
    int c = ci / 6, i = ci % 6;
    int ks = ci >> 5, q = (ci >> 3) & 3, j = ci & 7;
    W2k[kr * 12288 + ((ks * 4 + q) * 64 + d) * 8 + j] =
        f2bf(sym13(&W[(d * 32 + c) * 18], k, c_INV[r][i]));
  } else if (idx < 2138112) {
    int e = idx - 1990656;
    int r = e / 12288, rem = e % 12288, d = rem / 192, ci = rem % 192;
    int c = ci / 6, i = ci % 6;
    int ks = ci >> 5, q = (ci >> 3) & 3, j = ci & 7;
    Wck[r * 12288 + ((ks * 4 + q) * 64 + d) * 8 + j] =
        f2bf(sym13(&W[(d * 32 + c) * 18], 12, c_INV[r][i]));
  } else {
    int e = idx - 2138112;
    if (e < 192 * V) {
      int p = e / 192, ci = e % 192, c = ci / 6, i = ci % 6;
      float v = fm[(c * V + p) * 6 + i];
      fmTbf[e] = f2bf(v);
      out_fm[(c * V + p) * 6 + i] = v;
    }
  }
}

// ---------- k1: directions + de6 + W_dim -> cross_n [p][n][ci] + crossT_g [p][ci][n16] ----------
__global__ __launch_bounds__(256) void k1_cross(
    const int* __restrict__ nbi, const float* __restrict__ verts,
    const float* __restrict__ fm, const float* __restrict__ Wdim,
    unsigned short* __restrict__ cross_n,
    unsigned short* __restrict__ crossT_g, int V) {
  __shared__ float in_s[NN * 33 * 6];
  __shared__ float wd_s[33 * 32];
  __shared__ unsigned int cross_u[1536];   // [n][ci2] packed bf16 pairs
  __shared__ int nb_s[NN];
  int p = blockIdx.x, t = threadIdx.x;
  if (t < NN) nb_s[t] = nbi[p * NN + t];
  for (int idx = t; idx < 1056; idx += 256) wd_s[idx] = Wdim[idx];
  __syncthreads();
  for (int idx = t; idx < NN * 32; idx += 256) {
    int n = idx >> 5, c = idx & 31;
    const float* src = fm + ((size_t)c * V + nb_s[n]) * 6;
    float2 a  = *(const float2*)(src + 0);
    float2 b  = *(const float2*)(src + 2);
    float2 cd = *(const float2*)(src + 4);
    float* d = &in_s[(n * 33 + c) * 6];
    d[0] = a.x; d[1] = a.y; d[2] = b.x; d[3] = b.y; d[4] = cd.x; d[5] = cd.y;
  }
  if (t < NN) {
    int n = t, nb = nb_s[n];
    float px = verts[p * 3 + 0], py = verts[p * 3 + 1], pz = verts[p * 3 + 2];
    float dx = verts[nb * 3 + 0] - px, dy = verts[nb * 3 + 1] - py, dz = verts[nb * 3 + 2] - pz;
    float L = sqrtf(dx * dx + dy * dy + dz * dz);
    float inv = 1.0f / fmaxf(L, 1e-12f);
    dx *= inv; dy *= inv; dz *= inv;
    float de[12];
    #pragma unroll
    for (int v = 0; v < 12; ++v)
      de[v] = c_VS[v][0] * dx + c_VS[v][1] * dy + c_VS[v][2] * dz;
    #pragma unroll
    for (int j = 0; j < 6; ++j)
      in_s[(n * 33 + 32) * 6 + j] = fmaxf(de[c_C2V[j][0]], de[c_C2V[j][1]]);
  }
  __syncthreads();
  for (int idx = t; idx < 1536; idx += 256) {
    int n = idx / 96, cp2 = idx % 96;
    int ci0 = cp2 * 2, ci1 = ci0 + 1;
    int o0 = ci0 / 6, i0 = ci0 % 6;
    int o1 = ci1 / 6, i1 = ci1 % 6;
    float s0 = 0.f, s1 = 0.f;
    #pragma unroll
    for (int c = 0; c <= 32; ++c) {
      float f0 = in_s[(n * 33 + c) * 6 + i0];
      float f1 = in_s[(n * 33 + c) * 6 + i1];
      s0 = fmaf(wd_s[c * 32 + o0], f0, s0);
      s1 = fmaf(wd_s[c * 32 + o1], f1, s1);
    }
    cross_u[idx] = (unsigned int)f2bf(s0) | ((unsigned int)f2bf(s1) << 16);
  }
  __syncthreads();
  {
    const uint4* src = (const uint4*)cross_u;
    uint4* d1 = (uint4*)(cross_n + (size_t)p * 3072);
    for (int idx = t; idx < 384; idx += 256) d1[idx] = src[idx];
  }
  {
    unsigned int* d2 = (unsigned int*)(crossT_g + (size_t)p * 3072);
    for (int idx = t; idx < 1536; idx += 256) {
      int np = idx / 192, ci = idx % 192;
      unsigned int u0 = cross_u[(2 * np) * 96 + (ci >> 1)];
      unsigned int u1 = cross_u[(2 * np + 1) * 96 + (ci >> 1)];
      unsigned int h0 = (ci & 1) ? (u0 >> 16) : (u0 & 0xffffu);
      unsigned int h1 = (ci & 1) ? (u1 & 0xffff0000u) : (u1 << 16);
      d2[ci * 8 + np] = h0 | h1;
    }
  }
}

// ---------- k2: MFMA act GEMM + row-softmax + K16-MFMA nfm ----------
// 4 vertices/block, 512 threads (8 waves): wave = (tile-set tw, p-pair pw).
// nfm layout: [pg=p/4][row1152][pl=p%4][o24] -> each block fully writes
// contiguous 16row x 192B tile regions (L2 write-combines to full lines).
__global__ __launch_bounds__(512, 4) void k2_main(
    const unsigned short* __restrict__ A_bf,      // k-major
    const unsigned short* __restrict__ cross_n,   // [p][n][ci]
    const unsigned short* __restrict__ crossT_g,  // [p][ci][n16]
    unsigned short* __restrict__ nfm, int V) {
#ifdef HAVE_K16
  __shared__ __align__(16) unsigned short crossT[4][192][16];  // 24576 B
#else
  __shared__ __align__(16) unsigned short crossT[4][192][40];  // padded fallback
#endif
  int t = threadIdx.x;
  int w = t >> 6, lane = t & 63;
  int quad = lane >> 4, col = lane & 15;
  int p0 = blockIdx.x * 4;
  int pw = w & 1, tw = w >> 1;

  bf16x8 Afr[2][6];
  #pragma unroll
  for (int pi = 0; pi < 2; ++pi)
    #pragma unroll
    for (int ks = 0; ks < 6; ++ks)
      Afr[pi][ks] = *(const bf16x8*)(cross_n + (size_t)(p0 + pw * 2 + pi) * 3072 +
                                     col * 192 + ks * 32 + quad * 8);

#ifdef HAVE_K16
  // flat contiguous copy: 4 p x 192 ci x 16 n = 12288 ush = 1536 uint4
  for (int idx = t; idx < 1536; idx += 512) {
    *(uint4*)&((unsigned short*)crossT)[idx * 8] =
        *(const uint4*)(crossT_g + (size_t)p0 * 3072 + idx * 8);
  }
#else
  for (int idx = t; idx < 1536; idx += 512) {
    int p = idx / 384, rem = idx % 384, ci = rem >> 1, half = rem & 1;
    *(uint4*)&crossT[p][ci][half * 8] =
        *(const uint4*)(crossT_g + (size_t)(p0 + p) * 3072 + ci * 16 + half * 8);
  }
  for (int idx = t; idx < 1536; idx += 512) {
    int p = idx / 384, rem = idx % 384, ci = rem >> 1, half = rem & 1;
    *(uint4*)&crossT[p][ci][16 + half * 8] = make_uint4(0u, 0u, 0u, 0u);
  }
#endif
  __syncthreads();   // the only barrier

#ifndef HAVE_K16
  int s0l = quad * 32 + col;
  int s1l = s0l + 16;
#endif

  for (int rt = tw; rt < 72; rt += 4) {
    int h = rt / 9;
    // ---- phase A: actT[n][kr] for the wave's 2 vertices ----
    f32x4 acc[2];
    acc[0] = (f32x4){0.f, 0.f, 0.f, 0.f};
    acc[1] = (f32x4){0.f, 0.f, 0.f, 0.f};
    const unsigned short* Abase = A_bf + rt * 3072 + quad * 128 + col * 8;
    #pragma unroll
    for (int ks = 0; ks < 6; ++ks) {
      bf16x8 wf = *(const bf16x8*)(Abase + ks * 512);
      acc[0] = __builtin_amdgcn_mfma_f32_16x16x32_bf16(Afr[0][ks], wf, acc[0], 0, 0, 0);
      acc[1] = __builtin_amdgcn_mfma_f32_16x16x32_bf16(Afr[1][ks], wf, acc[1], 0, 0, 0);
    }
    int row0 = h * 24 + col;
    int row1 = min(h * 24 + 16 + col, 191);
    #pragma unroll
    for (int pi = 0; pi < 2; ++pi) {
      int p_i = pw * 2 + pi;
      // ---- softmax over n = rows ----
      float v0 = acc[pi][0], v1 = acc[pi][1], v2 = acc[pi][2], v3 = acc[pi][3];
      float mx = fmaxf(fmaxf(v0, v1), fmaxf(v2, v3));
      mx = fmaxf(mx, __shfl_xor(mx, 16));
      mx = fmaxf(mx, __shfl_xor(mx, 32));
      float e0 = __expf(v0 - mx), e1 = __expf(v1 - mx);
      float e2 = __expf(v2 - mx), e3 = __expf(v3 - mx);
      float s = (e0 + e1) + (e2 + e3);
      s += __shfl_xor(s, 16);
      s += __shfl_xor(s, 32);
      float inv = __builtin_amdgcn_rcpf(s);
      unsigned int lo = pack2(e0 * inv, e1 * inv);
      unsigned int hi = pack2(e2 * inv, e3 * inv);
      f32x4 o0 = (f32x4){0.f, 0.f, 0.f, 0.f}, o1 = o0;
#ifdef HAVE_K16
      union { uint2 u; bf16x4 v; } bcvt;
      bcvt.u = make_uint2(lo, hi);
      bf16x4 a0 = *(const bf16x4*)&crossT[p_i][row0][quad * 4];
      bf16x4 a1 = *(const bf16x4*)&crossT[p_i][row1][quad * 4];
      o0 = MFMA_K16(a0, bcvt.v, o0);
      o1 = MFMA_K16(a1, bcvt.v, o1);
#else
      unsigned int b0 = (unsigned int)__shfl((int)lo, s0l);
      unsigned int b1 = (unsigned int)__shfl((int)hi, s0l);
      unsigned int b2 = (unsigned int)__shfl((int)lo, s1l);
      unsigned int b3 = (unsigned int)__shfl((int)hi, s1l);
      bool vq = (quad < 2);
      union { uint4 u; bf16x8 v; } cvt;
      cvt.u = make_uint4(vq ? b0 : 0u, vq ? b1 : 0u, vq ? b2 : 0u, vq ? b3 : 0u);
      bf16x8 a0 = *(const bf16x8*)&crossT[p_i][row0][quad * 8];
      bf16x8 a1 = *(const bf16x8*)&crossT[p_i][row1][quad * 8];
      o0 = __builtin_amdgcn_mfma_f32_16x16x32_bf16(a0, cvt.v, o0, 0, 0, 0);
      o1 = __builtin_amdgcn_mfma_f32_16x16x32_bf16(a1, cvt.v, o1, 0, 0, 0);
#endif
      // ---- store: nfm[pg=blockIdx.x][row=rt*16+col][pl=p_i][o] ----
      size_t rowbase = (size_t)blockIdx.x * 110592 + (size_t)(rt * 16 + col) * 96 + p_i * 24;
      uint2 w0;
      w0.x = pack2(o0[0], o0[1]);
      w0.y = pack2(o0[2], o0[3]);
      *(uint2*)(nfm + rowbase + quad * 4) = w0;
      if (quad < 2) {
        uint2 w1;
        w1.x = pack2(o1[0], o1[1]);
        w1.y = pack2(o1[2], o1[3]);
        *(uint2*)(nfm + rowbase + 16 + quad * 4) = w1;
      }
    }
  }
}

// ---------- k3: MFMA feat GEMMs + center + fused c2v max -> out ----------
// grid (V/32, 6), 512 threads: waves 0-3 -> r0=c2v[j][0] (K-split 4),
// waves 4-7 -> r1. nfm layout [pg][row1152][pl4][o24]: lanes col0..3 (pl 0..3)
// cover contiguous 192B runs per (row, pg).
__global__ __launch_bounds__(512) void k3_feat(
    const unsigned short* __restrict__ W2k,
    const unsigned short* __restrict__ Wck,
    const unsigned short* __restrict__ fmTbf,
    const unsigned short* __restrict__ nfm,
    float* __restrict__ out, int V) {
  __shared__ float red[2][3][32][64];   // 49152 B
  int pb = blockIdx.x, j = blockIdx.y;
  int t = threadIdx.x, w = t >> 6, lane = t & 63;
  int rhalf = w >> 2, kw = w & 3;
  int r = c_C2V[j][rhalf];
  int quad = lane >> 4, col = lane & 15;
  int p0 = pb * 32;
  f32x4 acc[4][2];
  #pragma unroll
  for (int m = 0; m < 4; ++m)
    #pragma unroll
    for (int jj = 0; jj < 2; ++jj) acc[m][jj] = (f32x4){0.f, 0.f, 0.f, 0.f};

  // per-(ks) offsets into a vertex's nfm block: row = hh*144 + kr, elem = row*96 + oo
  int base24[6];
  #pragma unroll
  for (int ks = 0; ks < 6; ++ks) {
    int ci = ks * 32 + quad * 8;
    int hh = ci / 24, oo = ci - hh * 24;
    base24[ks] = hh * 13824 + oo;   // hh*144*96 + oo
  }

  int pA = p0 + col, pB = p0 + 16 + col;
  const unsigned short* Bn0 = nfm + (size_t)(pA >> 2) * 110592 + (pA & 3) * 24;
  const unsigned short* Bn1 = nfm + (size_t)(pB >> 2) * 110592 + (pB & 3) * 24;
  const unsigned short* Bc0 = fmTbf + (size_t)pA * 192;
  const unsigned short* Bc1 = fmTbf + (size_t)pB * 192;

  int nkb = (kw == 3) ? 4 : 3;
  for (int i = 0; i < nkb; ++i) {
    int kb = kw * 3 + i;   // kw=3,i=3 -> 12 (center)
    const unsigned short* Ab;
    int kr96 = 0;
    if (kb < 12) { Ab = W2k + (size_t)(kb * 12 + r) * 12288; kr96 = (kb * 12 + r) * 96; }
    else         { Ab = Wck + (size_t)r * 12288; }
    const unsigned short* Albase = Ab + quad * 512 + col * 8;
    #pragma unroll
    for (int ks = 0; ks < 6; ++ks) {
      bf16x8 b0, b1;
      if (kb < 12) {
        b0 = *(const bf16x8*)(Bn0 + base24[ks] + kr96);
        b1 = *(const bf16x8*)(Bn1 + base24[ks] + kr96);
      } else {
        int ko = ks * 32 + quad * 8;
        b0 = *(const bf16x8*)(Bc0 + ko);
        b1 = *(const bf16x8*)(Bc1 + ko);
      }
      #pragma unroll
      for (int m = 0; m < 4; ++m) {
        bf16x8 a = *(const bf16x8*)(Albase + ks * 2048 + m * 128);
        acc[m][0] = __builtin_amdgcn_mfma_f32_16x16x32_bf16(a, b0, acc[m][0], 0, 0, 0);
        acc[m][1] = __builtin_amdgcn_mfma_f32_16x16x32_bf16(a, b1, acc[m][1], 0, 0, 0);
      }
    }
  }
  if (kw > 0) {
    #pragma unroll
    for (int m = 0; m < 4; ++m)
      #pragma unroll
      for (int jj = 0; jj < 2; ++jj)
        #pragma unroll
        for (int rr = 0; rr < 4; ++rr)
          red[rhalf][kw - 1][m * 8 + jj * 4 + rr][lane] = acc[m][jj][rr];
  }
  __syncthreads();
  if (kw == 0) {
    #pragma unroll
    for (int m = 0; m < 4; ++m)
      #pragma unroll
      for (int jj = 0; jj < 2; ++jj)
        #pragma unroll
        for (int rr = 0; rr < 4; ++rr) {
          int ri = m * 8 + jj * 4 + rr;
          acc[m][jj][rr] += red[rhalf][0][ri][lane] + red[rhalf][1][ri][lane] + red[rhalf][2][ri][lane];
        }
  }
  if (w == 4) {
    #pragma unroll
    for (int m = 0; m < 4; ++m)
      #pragma unroll
      for (int jj = 0; jj < 2; ++jj)
        #pragma unroll
        for (int rr = 0; rr < 4; ++rr)
          red[1][0][m * 8 + jj * 4 + rr][lane] = acc[m][jj][rr];
  }
  __syncthreads();
  if (w == 0) {
    #pragma unroll
    for (int m = 0; m < 4; ++m)
      #pragma unroll
      for (int jj = 0; jj < 2; ++jj)
        #pragma unroll
        for (int rr = 0; rr < 4; ++rr) {
          float v = fmaxf(acc[m][jj][rr], red[1][0][m * 8 + jj * 4 + rr][lane]);
          int d = m * 16 + quad * 4 + rr;
          int p = p0 + jj * 16 + col;
          out[((size_t)d * V + p) * 6 + j] = v;
        }
  }
}

// ---------- host ----------
extern "C" void kernel_launch(void* const* d_in, const int* in_sizes, int n_in,
                              void* d_out, int out_size, void* d_ws, size_t ws_size,
                              hipStream_t stream) {
  const int* nbi = (const int*)d_in[0];
  const float* verts = (const float*)d_in[1];
  const float* fm = (const float*)d_in[2];
  const float* Wdim = (const float*)d_in[3];
  const float* W = (const float*)d_in[4];
  const float* Wdir = (const float*)d_in[5];
  float* out = (float*)d_out;
  float* ws = (float*)d_ws;
  int V = in_sizes[0] / NN;   // 2048

  unsigned short* A_bf  = (unsigned short*)ws;             // 221184 ush
  unsigned short* W2k   = (unsigned short*)(ws + 110592);  // 1769472 ush
  unsigned short* Wck   = (unsigned short*)(ws + 995328);  // 147456 ush
  unsigned short* fmTbf = (unsigned short*)(ws + 1069056); // 192*V ush
  size_t o = 1069056 + (size_t)96 * V;
  unsigned short* cross_n = (unsigned short*)(ws + o);     // 3072*V ush [p][n][ci]
  o += (size_t)1536 * V;
  unsigned short* crossT_g = (unsigned short*)(ws + o);    // 3072*V ush [p][ci][n16]
  o += (size_t)1536 * V;
  unsigned short* nfm = (unsigned short*)(ws + o);         // 27648*V ush [pg][row1152][pl4][o24]

  int n0 = 2138112 + 192 * V;
  k0_expand<<<(n0 + 255) / 256, 256, 0, stream>>>(W, Wdir, fm, A_bf, W2k, Wck, fmTbf,
                                                  out + (size_t)DO * V * 6, V);
  k1_cross<<<V, 256, 0, stream>>>(nbi, verts, fm, Wdim, cross_n, crossT_g, V);
  k2_main<<<V / 4, 512, 0, stream>>>(A_bf, cross_n, crossT_g, nfm, V);
  k3_feat<<<dim3(V / 32, 6), 512, 0, stream>>>(W2k, Wck, fmTbf, nfm, out, V);
}

// Round 9
// 178.650 us; speedup vs baseline: 1.0701x; 1.0084x over previous
//
#include <hip/hip_runtime.h>
#include <cstdint>
#include <cstddef>

#define NN 16   // neighbors
#define DI 32
#define DO 64

typedef short bf16x8 __attribute__((ext_vector_type(8)));
typedef short bf16x4 __attribute__((ext_vector_type(4)));
typedef float f32x4 __attribute__((ext_vector_type(4)));

// K=16 bf16 MFMA: B-operand layout (k=quad*4+j, col) == phase-A C-layout.
#if defined(__has_builtin)
#  if __has_builtin(__builtin_amdgcn_mfma_f32_16x16x16_bf16)
#    define MFMA_K16(a, b, c) __builtin_amdgcn_mfma_f32_16x16x16_bf16(a, b, c, 0, 0, 0)
#    define HAVE_K16 1
#  elif __has_builtin(__builtin_amdgcn_mfma_f32_16x16x16bf16_1k)
#    define MFMA_K16(a, b, c) __builtin_amdgcn_mfma_f32_16x16x16bf16_1k(a, b, c, 0, 0, 0)
#    define HAVE_K16 1
#  endif
#  if __has_builtin(__builtin_amdgcn_cvt_pk_bf16_f32)
#    define HAVE_PKBF 1
#  endif
#endif

// ---------- tables ----------
__device__ __constant__ int c_INV[12][6] = {
  {0,1,2,3,4,5},{0,5,4,3,2,1},{4,3,0,5,2,1},{1,2,4,3,5,0},
  {3,5,2,0,4,1},{1,4,3,5,0,2},{4,0,3,1,2,5},{1,0,2,4,3,5},
  {4,1,2,5,0,3},{3,1,4,0,2,5},{2,1,4,5,3,0},{4,5,0,3,1,2}};
__device__ __constant__ int c_ROLL[5][6] = {
  {0,1,2,3,4,5},{0,2,3,4,5,1},{0,3,4,5,1,2},{0,4,5,1,2,3},{0,5,1,2,3,4}};
__device__ __constant__ float c_VS[12][3] = {
  {0.f, 0.5257311121f, 0.8506508084f},
  {0.f, 0.5257311121f, -0.8506508084f},
  {0.f, -0.5257311121f, 0.8506508084f},
  {0.f, -0.5257311121f, -0.8506508084f},
  {0.5257311121f, 0.8506508084f, 0.f},
  {0.5257311121f, -0.8506508084f, 0.f},
  {-0.5257311121f, 0.8506508084f, 0.f},
  {-0.5257311121f, -0.8506508084f, 0.f},
  {0.8506508084f, 0.f, 0.5257311121f},
  {0.8506508084f, 0.f, -0.5257311121f},
  {-0.8506508084f, 0.f, 0.5257311121f},
  {-0.8506508084f, 0.f, -0.5257311121f}};
__device__ __constant__ int c_C2V[6][2] = {{0,1},{6,7},{2,11},{4,9},{5,8},{3,10}};

// ---------- helpers ----------
__device__ inline unsigned short f2bf(float f) {
  unsigned int u = __float_as_uint(f);
  unsigned int r = (u + 0x7fffu + ((u >> 16) & 1u)) >> 16;   // RNE
  return (unsigned short)r;
}
__device__ inline unsigned int pk2(float a, float b) {
#ifdef HAVE_PKBF
  typedef __bf16 bf16v2 __attribute__((ext_vector_type(2)));
  union { bf16v2 v; unsigned int u; } cv;
  cv.v = __builtin_amdgcn_cvt_pk_bf16_f32(a, b);
  return cv.u;
#else
  return (unsigned int)f2bf(a) | ((unsigned int)f2bf(b) << 16);
#endif
}
__device__ inline unsigned short f2bf_fast(float a) {
  return (unsigned short)(pk2(a, a) & 0xffffu);
}

__device__ inline float sym13(const float* __restrict__ w, int k, int j) {
  if (k == 0)  return w[j == 0 ? 0 : 1];
  if (k == 1)  return w[j == 0 ? 2 : 3];
  if (k == 12) return w[j == 0 ? 4 : 5];
  int a = (k - 2) / 5, rr = (k - 2) % 5;
  return w[6 + a * 6 + c_ROLL[rr][j]];
}

// ---------- k0: weight expansion (k-major bf16) + fmT + wdB frags + passthrough ----------
__global__ __launch_bounds__(256) void k0_expand(
    const float* __restrict__ W, const float* __restrict__ Wdir,
    const float* __restrict__ fm, const float* __restrict__ Wdim,
    unsigned short* __restrict__ A_bf,
    unsigned short* __restrict__ W2k,
    unsigned short* __restrict__ Wck,
    unsigned short* __restrict__ fmTbf,   // [V][192] bf16
    unsigned short* __restrict__ wdB,     // 2048: B-frags of padded W_dim
    float* __restrict__ out_fm, int V) {
  int idx = blockIdx.x * 256 + threadIdx.x;
  if (idx < 221184) {
    int row = idx / 192, ci = idx % 192;
    int h = row / 144, k = (row / 12) % 12, r = row % 12;
    int c = ci / 6, i = ci % 6;
    int rt = row >> 4, rl = row & 15;
    int ks = ci >> 5, q = (ci >> 3) & 3, j = ci & 7;
    A_bf[(((rt * 6 + ks) * 4 + q) * 16 + rl) * 8 + j] =
        f2bf_fast(0.5f * sym13(&Wdir[(h * 32 + c) * 18], k, c_INV[r][i]));
  } else if (idx < 1990656) {
    int e = idx - 221184;
    int kr = e / 12288, rem = e % 12288;
    int k = kr / 12, r = kr % 12, d = rem / 192, ci = rem % 192;
    int c = ci / 6, i = ci % 6;
    int ks = ci >> 5, q = (ci >> 3) & 3, j = ci & 7;
    W2k[kr * 12288 + ((ks * 4 + q) * 64 + d) * 8 + j] =
        f2bf_fast(sym13(&W[(d * 32 + c) * 18], k, c_INV[r][i]));
  } else if (idx < 2138112) {
    int e = idx - 1990656;
    int r = e / 12288, rem = e % 12288, d = rem / 192, ci = rem % 192;
    int c = ci / 6, i = ci % 6;
    int ks = ci >> 5, q = (ci >> 3) & 3, j = ci & 7;
    Wck[r * 12288 + ((ks * 4 + q) * 64 + d) * 8 + j] =
        f2bf_fast(sym13(&W[(d * 32 + c) * 18], 12, c_INV[r][i]));
  } else if (idx < 2138112 + 192 * V) {
    int e = idx - 2138112;
    int p = e / 192, ci = e % 192, c = ci / 6, i = ci % 6;
    float v = fm[(c * V + p) * 6 + i];
    fmTbf[e] = f2bf_fast(v);
    out_fm[(c * V + p) * 6 + i] = v;
  } else {
    int e = idx - (2138112 + 192 * V);
    if (e < 2048) {
      // wdB[((ot*2+kc)*64 + lane)*8 + j]: k = kc*32 + (lane>>4)*8 + j, o = ot*16 + (lane&15)
      int j = e & 7, lane = (e >> 3) & 63, kc = (e >> 9) & 1, ot = e >> 10;
      int k = kc * 32 + (lane >> 4) * 8 + j;
      int o = ot * 16 + (lane & 15);
      wdB[e] = (k <= 32) ? f2bf_fast(Wdim[k * 32 + o]) : (unsigned short)0;
    }
  }
}

// ---------- k1: MFMA W_dim contraction, wave-per-vertex, barrier-free ----------
// in matrix: [m = n*6+i (96)][k = c (33, padded to 64)] bf16 in LDS.
// D[m][o] = sum_c in*wd -> cross[n][ci=o*6+i]; emits cross_n + crossT_g.
__global__ __launch_bounds__(256) void k1_cross(
    const int* __restrict__ nbi, const float* __restrict__ verts,
    const float* __restrict__ fm, const unsigned short* __restrict__ wdB,
    unsigned short* __restrict__ cross_n,
    unsigned short* __restrict__ crossT_g, int V) {
  __shared__ __align__(16) unsigned short in_bf[4][96][64];   // 49152 B
  int t = threadIdx.x, w = t >> 6, lane = t & 63;
  int quad = lane >> 4, col = lane & 15;
  int p = blockIdx.x * 4 + w;
  unsigned short* mybuf = &in_bf[w][0][0];

  // zero cols 32..63 (de at col 32 overwrites; same-wave DS is in-order)
  for (int z = lane; z < 384; z += 64) {
    int m = z >> 2, q = z & 3;
    *(uint4*)&mybuf[m * 64 + 32 + q * 8] = make_uint4(0u, 0u, 0u, 0u);
  }

  float px = verts[p * 3 + 0], py = verts[p * 3 + 1], pz = verts[p * 3 + 2];
  for (int idx = lane; idx < 528; idx += 64) {
    int n = idx / 33, c = idx - n * 33;
    int nb = nbi[p * 16 + n];
    if (c < 32) {
      const float* src = fm + ((size_t)c * V + nb) * 6;
      float2 a  = *(const float2*)(src + 0);
      float2 b  = *(const float2*)(src + 2);
      float2 cd = *(const float2*)(src + 4);
      unsigned short* dst = &mybuf[(n * 6) * 64 + c];
      dst[0 * 64] = f2bf_fast(a.x);
      dst[1 * 64] = f2bf_fast(a.y);
      dst[2 * 64] = f2bf_fast(b.x);
      dst[3 * 64] = f2bf_fast(b.y);
      dst[4 * 64] = f2bf_fast(cd.x);
      dst[5 * 64] = f2bf_fast(cd.y);
    } else {
      float qx = verts[nb * 3 + 0] - px;
      float qy = verts[nb * 3 + 1] - py;
      float qz = verts[nb * 3 + 2] - pz;
      float L = sqrtf(qx * qx + qy * qy + qz * qz);
      float inv = 1.0f / fmaxf(L, 1e-12f);
      qx *= inv; qy *= inv; qz *= inv;
      float de[12];
      #pragma unroll
      for (int v = 0; v < 12; ++v)
        de[v] = c_VS[v][0] * qx + c_VS[v][1] * qy + c_VS[v][2] * qz;
      #pragma unroll
      for (int j = 0; j < 6; ++j)
        mybuf[(n * 6 + j) * 64 + 32] = f2bf_fast(fmaxf(de[c_C2V[j][0]], de[c_C2V[j][1]]));
    }
  }

  // B-frags (block-invariant, from global; L2-hot)
  bf16x8 Bf[2][2];
  #pragma unroll
  for (int ot = 0; ot < 2; ++ot)
    #pragma unroll
    for (int kc = 0; kc < 2; ++kc)
      Bf[ot][kc] = *(const bf16x8*)(wdB + (size_t)((ot * 2 + kc) * 64 + lane) * 8);

  asm volatile("s_waitcnt lgkmcnt(0)" ::: "memory");   // gather complete (this wave)

  f32x4 D[6][2];
  #pragma unroll
  for (int mt = 0; mt < 6; ++mt) {
    bf16x8 a0 = *(const bf16x8*)&mybuf[(mt * 16 + col) * 64 + quad * 8];
    bf16x8 a1 = *(const bf16x8*)&mybuf[(mt * 16 + col) * 64 + 32 + quad * 8];
    #pragma unroll
    for (int ot = 0; ot < 2; ++ot) {
      f32x4 acc = (f32x4){0.f, 0.f, 0.f, 0.f};
      acc = __builtin_amdgcn_mfma_f32_16x16x32_bf16(a0, Bf[ot][0], acc, 0, 0, 0);
      acc = __builtin_amdgcn_mfma_f32_16x16x32_bf16(a1, Bf[ot][1], acc, 0, 0, 0);
      D[mt][ot] = acc;
    }
  }

  asm volatile("s_waitcnt lgkmcnt(0)" ::: "memory");   // A-frag reads drained
  // epilogue: scatter D -> crossL[ci][n16] (aliases this wave's in_bf region)
  unsigned short* crossL = mybuf;
  #pragma unroll
  for (int mt = 0; mt < 6; ++mt) {
    #pragma unroll
    for (int ot = 0; ot < 2; ++ot) {
      #pragma unroll
      for (int r = 0; r < 4; ++r) {
        int m = mt * 16 + quad * 4 + r;
        int n = m / 6, i = m - n * 6;
        int ci = (ot * 16 + col) * 6 + i;
        crossL[ci * 16 + n] = f2bf_fast(D[mt][ot][r]);
      }
    }
  }
  asm volatile("s_waitcnt lgkmcnt(0)" ::: "memory");

  // crossT_g: verbatim copy of crossL (layout [ci][n16])
  {
    uint4* ct = (uint4*)(crossT_g + (size_t)p * 3072);
    const uint4* cl4 = (const uint4*)crossL;
    for (int q = lane; q < 384; q += 64) ct[q] = cl4[q];
  }
  // cross_n[p][n][ci]: transpose reads
  {
    uint4* cn = (uint4*)(cross_n + (size_t)p * 3072);
    for (int q = lane; q < 384; q += 64) {
      int n = (q * 8) / 192, ci0 = (q * 8) % 192;
      unsigned int u[4];
      #pragma unroll
      for (int h2 = 0; h2 < 4; ++h2) {
        unsigned int lo = crossL[(ci0 + 2 * h2 + 0) * 16 + n];
        unsigned int hi = crossL[(ci0 + 2 * h2 + 1) * 16 + n];
        u[h2] = lo | (hi << 16);
      }
      cn[q] = make_uint4(u[0], u[1], u[2], u[3]);
    }
  }
}

// ---------- k2: MFMA act GEMM + row-softmax + K16-MFMA nfm ----------
// 4 vertices/block, 512 threads (8 waves): wave = (tile-set tw, p-pair pw).
// nfm layout: [pg=p/4][row1152][pl=p%4][o24]
__global__ __launch_bounds__(512, 4) void k2_main(
    const unsigned short* __restrict__ A_bf,      // k-major
    const unsigned short* __restrict__ cross_n,   // [p][n][ci]
    const unsigned short* __restrict__ crossT_g,  // [p][ci][n16]
    unsigned short* __restrict__ nfm, int V) {
#ifdef HAVE_K16
  __shared__ __align__(16) unsigned short crossT[4][192][16];  // 24576 B
#else
  __shared__ __align__(16) unsigned short crossT[4][192][40];  // padded fallback
#endif
  int t = threadIdx.x;
  int w = t >> 6, lane = t & 63;
  int quad = lane >> 4, col = lane & 15;
  int p0 = blockIdx.x * 4;
  int pw = w & 1, tw = w >> 1;

  bf16x8 Afr[2][6];
  #pragma unroll
  for (int pi = 0; pi < 2; ++pi)
    #pragma unroll
    for (int ks = 0; ks < 6; ++ks)
      Afr[pi][ks] = *(const bf16x8*)(cross_n + (size_t)(p0 + pw * 2 + pi) * 3072 +
                                     col * 192 + ks * 32 + quad * 8);

#ifdef HAVE_K16
  for (int idx = t; idx < 1536; idx += 512) {
    *(uint4*)&((unsigned short*)crossT)[idx * 8] =
        *(const uint4*)(crossT_g + (size_t)p0 * 3072 + idx * 8);
  }
#else
  for (int idx = t; idx < 1536; idx += 512) {
    int p = idx / 384, rem = idx % 384, ci = rem >> 1, half = rem & 1;
    *(uint4*)&crossT[p][ci][half * 8] =
        *(const uint4*)(crossT_g + (size_t)(p0 + p) * 3072 + ci * 16 + half * 8);
  }
  for (int idx = t; idx < 1536; idx += 512) {
    int p = idx / 384, rem = idx % 384, ci = rem >> 1, half = rem & 1;
    *(uint4*)&crossT[p][ci][16 + half * 8] = make_uint4(0u, 0u, 0u, 0u);
  }
#endif
  __syncthreads();   // the only barrier

#ifndef HAVE_K16
  int s0l = quad * 32 + col;
  int s1l = s0l + 16;
#endif

  for (int rt = tw; rt < 72; rt += 4) {
    int h = rt / 9;
    f32x4 acc[2];
    acc[0] = (f32x4){0.f, 0.f, 0.f, 0.f};
    acc[1] = (f32x4){0.f, 0.f, 0.f, 0.f};
    const unsigned short* Abase = A_bf + rt * 3072 + quad * 128 + col * 8;
    #pragma unroll
    for (int ks = 0; ks < 6; ++ks) {
      bf16x8 wf = *(const bf16x8*)(Abase + ks * 512);
      acc[0] = __builtin_amdgcn_mfma_f32_16x16x32_bf16(Afr[0][ks], wf, acc[0], 0, 0, 0);
      acc[1] = __builtin_amdgcn_mfma_f32_16x16x32_bf16(Afr[1][ks], wf, acc[1], 0, 0, 0);
    }
    int row0 = h * 24 + col;
    int row1 = min(h * 24 + 16 + col, 191);
    #pragma unroll
    for (int pi = 0; pi < 2; ++pi) {
      int p_i = pw * 2 + pi;
      float v0 = acc[pi][0], v1 = acc[pi][1], v2 = acc[pi][2], v3 = acc[pi][3];
      float mx = fmaxf(fmaxf(v0, v1), fmaxf(v2, v3));
      mx = fmaxf(mx, __shfl_xor(mx, 16));
      mx = fmaxf(mx, __shfl_xor(mx, 32));
      float e0 = __expf(v0 - mx), e1 = __expf(v1 - mx);
      float e2 = __expf(v2 - mx), e3 = __expf(v3 - mx);
      float s = (e0 + e1) + (e2 + e3);
      s += __shfl_xor(s, 16);
      s += __shfl_xor(s, 32);
      float inv = __builtin_amdgcn_rcpf(s);
      unsigned int lo = pk2(e0 * inv, e1 * inv);
      unsigned int hi = pk2(e2 * inv, e3 * inv);
      f32x4 o0 = (f32x4){0.f, 0.f, 0.f, 0.f}, o1 = o0;
#ifdef HAVE_K16
      union { uint2 u; bf16x4 v; } bcvt;
      bcvt.u = make_uint2(lo, hi);
      bf16x4 a0 = *(const bf16x4*)&crossT[p_i][row0][quad * 4];
      bf16x4 a1 = *(const bf16x4*)&crossT[p_i][row1][quad * 4];
      o0 = MFMA_K16(a0, bcvt.v, o0);
      o1 = MFMA_K16(a1, bcvt.v, o1);
#else
      unsigned int b0 = (unsigned int)__shfl((int)lo, s0l);
      unsigned int b1 = (unsigned int)__shfl((int)hi, s0l);
      unsigned int b2 = (unsigned int)__shfl((int)lo, s1l);
      unsigned int b3 = (unsigned int)__shfl((int)hi, s1l);
      bool vq = (quad < 2);
      union { uint4 u; bf16x8 v; } cvt;
      cvt.u = make_uint4(vq ? b0 : 0u, vq ? b1 : 0u, vq ? b2 : 0u, vq ? b3 : 0u);
      bf16x8 a0 = *(const bf16x8*)&crossT[p_i][row0][quad * 8];
      bf16x8 a1 = *(const bf16x8*)&crossT[p_i][row1][quad * 8];
      o0 = __builtin_amdgcn_mfma_f32_16x16x32_bf16(a0, cvt.v, o0, 0, 0, 0);
      o1 = __builtin_amdgcn_mfma_f32_16x16x32_bf16(a1, cvt.v, o1, 0, 0, 0);
#endif
      size_t rowbase = (size_t)blockIdx.x * 110592 + (size_t)(rt * 16 + col) * 96 + p_i * 24;
      uint2 w0;
      w0.x = pk2(o0[0], o0[1]);
      w0.y = pk2(o0[2], o0[3]);
      *(uint2*)(nfm + rowbase + quad * 4) = w0;
      if (quad < 2) {
        uint2 w1;
        w1.x = pk2(o1[0], o1[1]);
        w1.y = pk2(o1[2], o1[3]);
        *(uint2*)(nfm + rowbase + 16 + quad * 4) = w1;
      }
    }
  }
}

// ---------- k3: MFMA feat GEMMs + center + fused c2v max -> out ----------
__global__ __launch_bounds__(512) void k3_feat(
    const unsigned short* __restrict__ W2k,
    const unsigned short* __restrict__ Wck,
    const unsigned short* __restrict__ fmTbf,
    const unsigned short* __restrict__ nfm,
    float* __restrict__ out, int V) {
  __shared__ float red[2][3][32][64];   // 49152 B
  int pb = blockIdx.x, j = blockIdx.y;
  int t = threadIdx.x, w = t >> 6, lane = t & 63;
  int rhalf = w >> 2, kw = w & 3;
  int r = c_C2V[j][rhalf];
  int quad = lane >> 4, col = lane & 15;
  int p0 = pb * 32;
  f32x4 acc[4][2];
  #pragma unroll
  for (int m = 0; m < 4; ++m)
    #pragma unroll
    for (int jj = 0; jj < 2; ++jj) acc[m][jj] = (f32x4){0.f, 0.f, 0.f, 0.f};

  int base24[6];
  #pragma unroll
  for (int ks = 0; ks < 6; ++ks) {
    int ci = ks * 32 + quad * 8;
    int hh = ci / 24, oo = ci - hh * 24;
    base24[ks] = hh * 13824 + oo;   // hh*144*96 + oo
  }

  int pA = p0 + col, pB = p0 + 16 + col;
  const unsigned short* Bn0 = nfm + (size_t)(pA >> 2) * 110592 + (pA & 3) * 24;
  const unsigned short* Bn1 = nfm + (size_t)(pB >> 2) * 110592 + (pB & 3) * 24;
  const unsigned short* Bc0 = fmTbf + (size_t)pA * 192;
  const unsigned short* Bc1 = fmTbf + (size_t)pB * 192;

  int nkb = (kw == 3) ? 4 : 3;
  for (int i = 0; i < nkb; ++i) {
    int kb = kw * 3 + i;   // kw=3,i=3 -> 12 (center)
    const unsigned short* Ab;
    int kr96 = 0;
    if (kb < 12) { Ab = W2k + (size_t)(kb * 12 + r) * 12288; kr96 = (kb * 12 + r) * 96; }
    else         { Ab = Wck + (size_t)r * 12288; }
    const unsigned short* Albase = Ab + quad * 512 + col * 8;
    #pragma unroll
    for (int ks = 0; ks < 6; ++ks) {
      bf16x8 b0, b1;
      if (kb < 12) {
        b0 = *(const bf16x8*)(Bn0 + base24[ks] + kr96);
        b1 = *(const bf16x8*)(Bn1 + base24[ks] + kr96);
      } else {
        int ko = ks * 32 + quad * 8;
        b0 = *(const bf16x8*)(Bc0 + ko);
        b1 = *(const bf16x8*)(Bc1 + ko);
      }
      #pragma unroll
      for (int m = 0; m < 4; ++m) {
        bf16x8 a = *(const bf16x8*)(Albase + ks * 2048 + m * 128);
        acc[m][0] = __builtin_amdgcn_mfma_f32_16x16x32_bf16(a, b0, acc[m][0], 0, 0, 0);
        acc[m][1] = __builtin_amdgcn_mfma_f32_16x16x32_bf16(a, b1, acc[m][1], 0, 0, 0);
      }
    }
  }
  if (kw > 0) {
    #pragma unroll
    for (int m = 0; m < 4; ++m)
      #pragma unroll
      for (int jj = 0; jj < 2; ++jj)
        #pragma unroll
        for (int rr = 0; rr < 4; ++rr)
          red[rhalf][kw - 1][m * 8 + jj * 4 + rr][lane] = acc[m][jj][rr];
  }
  __syncthreads();
  if (kw == 0) {
    #pragma unroll
    for (int m = 0; m < 4; ++m)
      #pragma unroll
      for (int jj = 0; jj < 2; ++jj)
        #pragma unroll
        for (int rr = 0; rr < 4; ++rr) {
          int ri = m * 8 + jj * 4 + rr;
          acc[m][jj][rr] += red[rhalf][0][ri][lane] + red[rhalf][1][ri][lane] + red[rhalf][2][ri][lane];
        }
  }
  if (w == 4) {
    #pragma unroll
    for (int m = 0; m < 4; ++m)
      #pragma unroll
      for (int jj = 0; jj < 2; ++jj)
        #pragma unroll
        for (int rr = 0; rr < 4; ++rr)
          red[1][0][m * 8 + jj * 4 + rr][lane] = acc[m][jj][rr];
  }
  __syncthreads();
  if (w == 0) {
    #pragma unroll
    for (int m = 0; m < 4; ++m)
      #pragma unroll
      for (int jj = 0; jj < 2; ++jj)
        #pragma unroll
        for (int rr = 0; rr < 4; ++rr) {
          float v = fmaxf(acc[m][jj][rr], red[1][0][m * 8 + jj * 4 + rr][lane]);
          int d = m * 16 + quad * 4 + rr;
          int p = p0 + jj * 16 + col;
          out[((size_t)d * V + p) * 6 + j] = v;
        }
  }
}

// ---------- host ----------
extern "C" void kernel_launch(void* const* d_in, const int* in_sizes, int n_in,
                              void* d_out, int out_size, void* d_ws, size_t ws_size,
                              hipStream_t stream) {
  const int* nbi = (const int*)d_in[0];
  const float* verts = (const float*)d_in[1];
  const float* fm = (const float*)d_in[2];
  const float* Wdim = (const float*)d_in[3];
  const float* W = (const float*)d_in[4];
  const float* Wdir = (const float*)d_in[5];
  float* out = (float*)d_out;
  float* ws = (float*)d_ws;
  int V = in_sizes[0] / NN;   // 2048

  unsigned short* A_bf  = (unsigned short*)ws;             // 221184 ush
  unsigned short* W2k   = (unsigned short*)(ws + 110592);  // 1769472 ush
  unsigned short* Wck   = (unsigned short*)(ws + 995328);  // 147456 ush
  unsigned short* fmTbf = (unsigned short*)(ws + 1069056); // 192*V ush
  size_t o = 1069056 + (size_t)96 * V;
  unsigned short* cross_n = (unsigned short*)(ws + o);     // 3072*V ush [p][n][ci]
  o += (size_t)1536 * V;
  unsigned short* crossT_g = (unsigned short*)(ws + o);    // 3072*V ush [p][ci][n16]
  o += (size_t)1536 * V;
  unsigned short* nfm = (unsigned short*)(ws + o);         // 27648*V ush [pg][row1152][pl4][o24]
  o += (size_t)13824 * V;
  unsigned short* wdB = (unsigned short*)(ws + o);         // 2048 ush

  int n0 = 2138112 + 192 * V + 2048;
  k0_expand<<<(n0 + 255) / 256, 256, 0, stream>>>(W, Wdir, fm, Wdim, A_bf, W2k, Wck, fmTbf,
                                                  wdB, out + (size_t)DO * V * 6, V);
  k1_cross<<<V / 4, 256, 0, stream>>>(nbi, verts, fm, wdB, cross_n, crossT_g, V);
  k2_main<<<V / 4, 512, 0, stream>>>(A_bf, cross_n, crossT_g, nfm, V);
  k3_feat<<<dim3(V / 32, 6), 512, 0, stream>>>(W2k, Wck, fmTbf, nfm, out, V);
}

// Round 10
// 158.054 us; speedup vs baseline: 1.2095x; 1.1303x over previous
//
#include <hip/hip_runtime.h>
#include <cstdint>
#include <cstddef>

#define NN 16   // neighbors
#define DI 32
#define DO 64

typedef short bf16x8 __attribute__((ext_vector_type(8)));
typedef short bf16x4 __attribute__((ext_vector_type(4)));
typedef float f32x4 __attribute__((ext_vector_type(4)));

#if defined(__has_builtin)
#  if __has_builtin(__builtin_amdgcn_mfma_f32_16x16x16_bf16)
#    define MFMA_K16(a, b, c) __builtin_amdgcn_mfma_f32_16x16x16_bf16(a, b, c, 0, 0, 0)
#    define HAVE_K16 1
#  elif __has_builtin(__builtin_amdgcn_mfma_f32_16x16x16bf16_1k)
#    define MFMA_K16(a, b, c) __builtin_amdgcn_mfma_f32_16x16x16bf16_1k(a, b, c, 0, 0, 0)
#    define HAVE_K16 1
#  endif
#  if __has_builtin(__builtin_amdgcn_cvt_pk_bf16_f32)
#    define HAVE_PKBF 1
#  endif
#endif

// ---------- tables ----------
__device__ __constant__ int c_INV[12][6] = {
  {0,1,2,3,4,5},{0,5,4,3,2,1},{4,3,0,5,2,1},{1,2,4,3,5,0},
  {3,5,2,0,4,1},{1,4,3,5,0,2},{4,0,3,1,2,5},{1,0,2,4,3,5},
  {4,1,2,5,0,3},{3,1,4,0,2,5},{2,1,4,5,3,0},{4,5,0,3,1,2}};
__device__ __constant__ int c_ROLL[5][6] = {
  {0,1,2,3,4,5},{0,2,3,4,5,1},{0,3,4,5,1,2},{0,4,5,1,2,3},{0,5,1,2,3,4}};
__device__ __constant__ float c_VS[12][3] = {
  {0.f, 0.5257311121f, 0.8506508084f},
  {0.f, 0.5257311121f, -0.8506508084f},
  {0.f, -0.5257311121f, 0.8506508084f},
  {0.f, -0.5257311121f, -0.8506508084f},
  {0.5257311121f, 0.8506508084f, 0.f},
  {0.5257311121f, -0.8506508084f, 0.f},
  {-0.5257311121f, 0.8506508084f, 0.f},
  {-0.5257311121f, -0.8506508084f, 0.f},
  {0.8506508084f, 0.f, 0.5257311121f},
  {0.8506508084f, 0.f, -0.5257311121f},
  {-0.8506508084f, 0.f, 0.5257311121f},
  {-0.8506508084f, 0.f, -0.5257311121f}};
__device__ __constant__ int c_C2V[6][2] = {{0,1},{6,7},{2,11},{4,9},{5,8},{3,10}};

// ---------- helpers ----------
__device__ inline unsigned short f2bf(float f) {
  unsigned int u = __float_as_uint(f);
  unsigned int r = (u + 0x7fffu + ((u >> 16) & 1u)) >> 16;   // RNE
  return (unsigned short)r;
}
__device__ inline unsigned int pk2(float a, float b) {
#ifdef HAVE_PKBF
  typedef __bf16 bf16v2 __attribute__((ext_vector_type(2)));
  union { bf16v2 v; unsigned int u; } cv;
  cv.v = __builtin_amdgcn_cvt_pk_bf16_f32(a, b);
  return cv.u;
#else
  return (unsigned int)f2bf(a) | ((unsigned int)f2bf(b) << 16);
#endif
}
__device__ inline unsigned short f2bf_fast(float a) {
  return (unsigned short)(pk2(a, a) & 0xffffu);
}

__device__ inline float sym13(const float* __restrict__ w, int k, int j) {
  if (k == 0)  return w[j == 0 ? 0 : 1];
  if (k == 1)  return w[j == 0 ? 2 : 3];
  if (k == 12) return w[j == 0 ? 4 : 5];
  int a = (k - 2) / 5, rr = (k - 2) % 5;
  return w[6 + a * 6 + c_ROLL[rr][j]];
}

// ---------- k0: weight expansion (k-major bf16) + fmT + wdB frags + passthrough ----------
__global__ __launch_bounds__(256) void k0_expand(
    const float* __restrict__ W, const float* __restrict__ Wdir,
    const float* __restrict__ fm, const float* __restrict__ Wdim,
    unsigned short* __restrict__ A_bf,
    unsigned short* __restrict__ W2k,
    unsigned short* __restrict__ Wck,
    unsigned short* __restrict__ fmTbf,   // [V][192] bf16
    unsigned short* __restrict__ wdB,     // 1024: B-frags of W_dim rows 0..31
    float* __restrict__ out_fm, int V) {
  int idx = blockIdx.x * 256 + threadIdx.x;
  if (idx < 221184) {
    int row = idx / 192, ci = idx % 192;
    int h = row / 144, k = (row / 12) % 12, r = row % 12;
    int c = ci / 6, i = ci % 6;
    int rt = row >> 4, rl = row & 15;
    int ks = ci >> 5, q = (ci >> 3) & 3, j = ci & 7;
    A_bf[(((rt * 6 + ks) * 4 + q) * 16 + rl) * 8 + j] =
        f2bf_fast(0.5f * sym13(&Wdir[(h * 32 + c) * 18], k, c_INV[r][i]));
  } else if (idx < 1990656) {
    int e = idx - 221184;
    int kr = e / 12288, rem = e % 12288;
    int k = kr / 12, r = kr % 12, d = rem / 192, ci = rem % 192;
    int c = ci / 6, i = ci % 6;
    int ks = ci >> 5, q = (ci >> 3) & 3, j = ci & 7;
    W2k[kr * 12288 + ((ks * 4 + q) * 64 + d) * 8 + j] =
        f2bf_fast(sym13(&W[(d * 32 + c) * 18], k, c_INV[r][i]));
  } else if (idx < 2138112) {
    int e = idx - 1990656;
    int r = e / 12288, rem = e % 12288, d = rem / 192, ci = rem % 192;
    int c = ci / 6, i = ci % 6;
    int ks = ci >> 5, q = (ci >> 3) & 3, j = ci & 7;
    Wck[r * 12288 + ((ks * 4 + q) * 64 + d) * 8 + j] =
        f2bf_fast(sym13(&W[(d * 32 + c) * 18], 12, c_INV[r][i]));
  } else if (idx < 2138112 + 192 * V) {
    int e = idx - 2138112;
    int p = e / 192, ci = e % 192, c = ci / 6, i = ci % 6;
    float v = fm[(c * V + p) * 6 + i];
    fmTbf[e] = f2bf_fast(v);
    out_fm[(c * V + p) * 6 + i] = v;
  } else {
    int e = idx - (2138112 + 192 * V);
    if (e < 1024) {
      // wdB[(ot*64 + lane)*8 + j]: k = (lane>>4)*8+j (<32), o = ot*16 + (lane&15)
      int j = e & 7, lane = (e >> 3) & 63, ot = e >> 9;
      int k = ((lane >> 4) & 3) * 8 + j;
      int o = ot * 16 + (lane & 15);
      wdB[e] = f2bf_fast(Wdim[k * 32 + o]);
    }
  }
}

// ---------- k12: fused cross (W_dim MFMA) + act GEMM + softmax + nfm ----------
// 2 vertices/block, 256 threads (4 waves), grid V/2 = 1024 -> 4 blocks/CU.
// Phase G: all waves gather fm->in_bf (bf16, K=32 exact) + de->de_s (fp32).
// Phase C: waves 0,1 compute cross via 16x16x32 MFMA + fp32 rank-1 de term,
//          write crossL[v][ci][n16] to LDS only (no global round-trip).
// Phase T: per-wave tile loop (18 tiles), barrier-free: act GEMM -> softmax ->
//          K16 MFMA -> direct global store. nfm layout [pg=p/2][row1152][48].
__global__ __launch_bounds__(256, 4) void k12_main(
    const int* __restrict__ nbi, const float* __restrict__ verts,
    const float* __restrict__ fm, const float* __restrict__ Wdim,
    const unsigned short* __restrict__ wdB,
    const unsigned short* __restrict__ A_bf,
    unsigned short* __restrict__ nfm, int V) {
  __shared__ __align__(16) unsigned short in_bf[2][96][40];  // 15360 B (stride 40: bank-spread)
  __shared__ __align__(16) float de_s[2][96];                // 768 B
  __shared__ __align__(16) unsigned short crossL[2][192][20];// 15360 B (stride 20: b64-align + spread)
  int t = threadIdx.x;
  int w = t >> 6, lane = t & 63;
  int quad = lane >> 4, col = lane & 15;
  int p0 = blockIdx.x * 2;
  int v = w & 1, hf = w >> 1;
  int p = p0 + v;

  // ---- phase G: gather (wave (v,hf) covers c = hf*16..hf*16+15 of vertex v) ----
  for (int i = lane; i < 256; i += 64) {
    int n = i >> 4, c = hf * 16 + (i & 15);
    int nb = nbi[p * 16 + n];
    const float* src = fm + ((size_t)c * V + nb) * 6;
    float2 a  = *(const float2*)(src + 0);
    float2 b  = *(const float2*)(src + 2);
    float2 cd = *(const float2*)(src + 4);
    unsigned short* dst = &in_bf[v][n * 6][c];
    dst[0 * 40] = f2bf_fast(a.x);
    dst[1 * 40] = f2bf_fast(a.y);
    dst[2 * 40] = f2bf_fast(b.x);
    dst[3 * 40] = f2bf_fast(b.y);
    dst[4 * 40] = f2bf_fast(cd.x);
    dst[5 * 40] = f2bf_fast(cd.y);
  }
  if (hf == 0 && lane < 16) {
    int n = lane, nb = nbi[p * 16 + n];
    float px = verts[p * 3 + 0], py = verts[p * 3 + 1], pz = verts[p * 3 + 2];
    float qx = verts[nb * 3 + 0] - px, qy = verts[nb * 3 + 1] - py, qz = verts[nb * 3 + 2] - pz;
    float L = sqrtf(qx * qx + qy * qy + qz * qz);
    float inv = 1.0f / fmaxf(L, 1e-12f);
    qx *= inv; qy *= inv; qz *= inv;
    float de[12];
    #pragma unroll
    for (int vv = 0; vv < 12; ++vv)
      de[vv] = c_VS[vv][0] * qx + c_VS[vv][1] * qy + c_VS[vv][2] * qz;
    #pragma unroll
    for (int j = 0; j < 6; ++j)
      de_s[v][n * 6 + j] = fmaxf(de[c_C2V[j][0]], de[c_C2V[j][1]]);
  }
  __syncthreads();

  // ---- phase C: cross MFMA (waves 0,1 -> vertex w) ----
  if (w < 2) {
    int vv = w;
    bf16x8 Bf[2];
    #pragma unroll
    for (int ot = 0; ot < 2; ++ot)
      Bf[ot] = *(const bf16x8*)(wdB + (size_t)(ot * 64 + lane) * 8);
    float wd32[2] = {Wdim[1024 + col], Wdim[1024 + 16 + col]};   // row c=32 (de), fp32
    f32x4 D[6][2];
    #pragma unroll
    for (int mt = 0; mt < 6; ++mt) {
      bf16x8 a0 = *(const bf16x8*)&in_bf[vv][mt * 16 + col][quad * 8];
      f32x4 du = *(const f32x4*)&de_s[vv][mt * 16 + quad * 4];
      #pragma unroll
      for (int ot = 0; ot < 2; ++ot) {
        f32x4 acc = (f32x4){0.f, 0.f, 0.f, 0.f};
        acc = __builtin_amdgcn_mfma_f32_16x16x32_bf16(a0, Bf[ot], acc, 0, 0, 0);
        #pragma unroll
        for (int r = 0; r < 4; ++r)
          acc[r] = fmaf(du[r], wd32[ot], acc[r]);
        D[mt][ot] = acc;
      }
    }
    // epilogue -> crossL[vv][ci][n]
    #pragma unroll
    for (int mt = 0; mt < 6; ++mt) {
      #pragma unroll
      for (int ot = 0; ot < 2; ++ot) {
        #pragma unroll
        for (int r = 0; r < 4; ++r) {
          int m = mt * 16 + quad * 4 + r;
          int n = m / 6, i = m - n * 6;
          crossL[vv][(ot * 16 + col) * 6 + i][n] = f2bf_fast(D[mt][ot][r]);
        }
      }
    }
  }
  __syncthreads();

  // ---- build Afr from crossL (transpose reads, one-time) ----
  bf16x8 Afr[2][6];
  #pragma unroll
  for (int pi = 0; pi < 2; ++pi) {
    #pragma unroll
    for (int ks = 0; ks < 6; ++ks) {
      union { unsigned short s[8]; bf16x8 v8; } u;
      #pragma unroll
      for (int j = 0; j < 8; ++j)
        u.s[j] = crossL[pi][ks * 32 + quad * 8 + j][col];
      Afr[pi][ks] = u.v8;
    }
  }

  // ---- phase T: 18 tile iterations per wave, barrier-free ----
  for (int rt = w; rt < 72; rt += 4) {
    int h = rt / 9;
    f32x4 acc[2];
    acc[0] = (f32x4){0.f, 0.f, 0.f, 0.f};
    acc[1] = (f32x4){0.f, 0.f, 0.f, 0.f};
    const unsigned short* Abase = A_bf + rt * 3072 + quad * 128 + col * 8;
    #pragma unroll
    for (int ks = 0; ks < 6; ++ks) {
      bf16x8 wf = *(const bf16x8*)(Abase + ks * 512);
      acc[0] = __builtin_amdgcn_mfma_f32_16x16x32_bf16(Afr[0][ks], wf, acc[0], 0, 0, 0);
      acc[1] = __builtin_amdgcn_mfma_f32_16x16x32_bf16(Afr[1][ks], wf, acc[1], 0, 0, 0);
    }
    int row0 = h * 24 + col;
    int row1 = min(h * 24 + 16 + col, 191);
    #pragma unroll
    for (int pi = 0; pi < 2; ++pi) {
      float v0 = acc[pi][0], v1 = acc[pi][1], v2 = acc[pi][2], v3 = acc[pi][3];
      float mx = fmaxf(fmaxf(v0, v1), fmaxf(v2, v3));
      mx = fmaxf(mx, __shfl_xor(mx, 16));
      mx = fmaxf(mx, __shfl_xor(mx, 32));
      float e0 = __expf(v0 - mx), e1 = __expf(v1 - mx);
      float e2 = __expf(v2 - mx), e3 = __expf(v3 - mx);
      float s = (e0 + e1) + (e2 + e3);
      s += __shfl_xor(s, 16);
      s += __shfl_xor(s, 32);
      float inv = __builtin_amdgcn_rcpf(s);
      unsigned int lo = pk2(e0 * inv, e1 * inv);
      unsigned int hi = pk2(e2 * inv, e3 * inv);
      f32x4 o0 = (f32x4){0.f, 0.f, 0.f, 0.f}, o1 = o0;
#ifdef HAVE_K16
      union { uint2 u; bf16x4 v4; } bcvt;
      bcvt.u = make_uint2(lo, hi);
      bf16x4 a0 = *(const bf16x4*)&crossL[pi][row0][quad * 4];
      bf16x4 a1 = *(const bf16x4*)&crossL[pi][row1][quad * 4];
      o0 = MFMA_K16(a0, bcvt.v4, o0);
      o1 = MFMA_K16(a1, bcvt.v4, o1);
#else
      int s0l = quad * 32 + col, s1l = s0l + 16;
      unsigned int b0 = (unsigned int)__shfl((int)lo, s0l);
      unsigned int b1 = (unsigned int)__shfl((int)hi, s0l);
      unsigned int b2 = (unsigned int)__shfl((int)lo, s1l);
      unsigned int b3 = (unsigned int)__shfl((int)hi, s1l);
      bool vq = (quad < 2);
      union { uint4 u; bf16x8 v8; } cvt;
      cvt.u = make_uint4(vq ? b0 : 0u, vq ? b1 : 0u, vq ? b2 : 0u, vq ? b3 : 0u);
      union { unsigned short s[8]; bf16x8 v8; } ua0, ua1;
      #pragma unroll
      for (int j = 0; j < 8; ++j) {
        int nn = quad * 8 + j;
        ua0.s[j] = (nn < 16) ? crossL[pi][row0][nn] : (unsigned short)0;
        ua1.s[j] = (nn < 16) ? crossL[pi][row1][nn] : (unsigned short)0;
      }
      o0 = __builtin_amdgcn_mfma_f32_16x16x32_bf16(ua0.v8, cvt.v8, o0, 0, 0, 0);
      o1 = __builtin_amdgcn_mfma_f32_16x16x32_bf16(ua1.v8, cvt.v8, o1, 0, 0, 0);
#endif
      size_t rowbase = (size_t)blockIdx.x * 55296 + (size_t)(rt * 16 + col) * 48 + pi * 24;
      uint2 w0;
      w0.x = pk2(o0[0], o0[1]);
      w0.y = pk2(o0[2], o0[3]);
      *(uint2*)(nfm + rowbase + quad * 4) = w0;
      if (quad < 2) {
        uint2 w1;
        w1.x = pk2(o1[0], o1[1]);
        w1.y = pk2(o1[2], o1[3]);
        *(uint2*)(nfm + rowbase + 16 + quad * 4) = w1;
      }
    }
  }
}

// ---------- k3: MFMA feat GEMMs + center + fused c2v max -> out ----------
// nfm layout [pg=p/2][row1152][48]
__global__ __launch_bounds__(512) void k3_feat(
    const unsigned short* __restrict__ W2k,
    const unsigned short* __restrict__ Wck,
    const unsigned short* __restrict__ fmTbf,
    const unsigned short* __restrict__ nfm,
    float* __restrict__ out, int V) {
  __shared__ float red[2][3][32][64];   // 49152 B
  int pb = blockIdx.x, j = blockIdx.y;
  int t = threadIdx.x, w = t >> 6, lane = t & 63;
  int rhalf = w >> 2, kw = w & 3;
  int r = c_C2V[j][rhalf];
  int quad = lane >> 4, col = lane & 15;
  int p0 = pb * 32;
  f32x4 acc[4][2];
  #pragma unroll
  for (int m = 0; m < 4; ++m)
    #pragma unroll
    for (int jj = 0; jj < 2; ++jj) acc[m][jj] = (f32x4){0.f, 0.f, 0.f, 0.f};

  int base24[6];
  #pragma unroll
  for (int ks = 0; ks < 6; ++ks) {
    int ci = ks * 32 + quad * 8;
    int hh = ci / 24, oo = ci - hh * 24;
    base24[ks] = hh * 6912 + oo;   // hh*144*48 + oo
  }

  int pA = p0 + col, pB = p0 + 16 + col;
  const unsigned short* Bn0 = nfm + (size_t)(pA >> 1) * 55296 + (pA & 1) * 24;
  const unsigned short* Bn1 = nfm + (size_t)(pB >> 1) * 55296 + (pB & 1) * 24;
  const unsigned short* Bc0 = fmTbf + (size_t)pA * 192;
  const unsigned short* Bc1 = fmTbf + (size_t)pB * 192;

  int nkb = (kw == 3) ? 4 : 3;
  for (int i = 0; i < nkb; ++i) {
    int kb = kw * 3 + i;   // kw=3,i=3 -> 12 (center)
    const unsigned short* Ab;
    int kr48 = 0;
    if (kb < 12) { Ab = W2k + (size_t)(kb * 12 + r) * 12288; kr48 = (kb * 12 + r) * 48; }
    else         { Ab = Wck + (size_t)r * 12288; }
    const unsigned short* Albase = Ab + quad * 512 + col * 8;
    #pragma unroll
    for (int ks = 0; ks < 6; ++ks) {
      bf16x8 b0, b1;
      if (kb < 12) {
        b0 = *(const bf16x8*)(Bn0 + base24[ks] + kr48);
        b1 = *(const bf16x8*)(Bn1 + base24[ks] + kr48);
      } else {
        int ko = ks * 32 + quad * 8;
        b0 = *(const bf16x8*)(Bc0 + ko);
        b1 = *(const bf16x8*)(Bc1 + ko);
      }
      #pragma unroll
      for (int m = 0; m < 4; ++m) {
        bf16x8 a = *(const bf16x8*)(Albase + ks * 2048 + m * 128);
        acc[m][0] = __builtin_amdgcn_mfma_f32_16x16x32_bf16(a, b0, acc[m][0], 0, 0, 0);
        acc[m][1] = __builtin_amdgcn_mfma_f32_16x16x32_bf16(a, b1, acc[m][1], 0, 0, 0);
      }
    }
  }
  if (kw > 0) {
    #pragma unroll
    for (int m = 0; m < 4; ++m)
      #pragma unroll
      for (int jj = 0; jj < 2; ++jj)
        #pragma unroll
        for (int rr = 0; rr < 4; ++rr)
          red[rhalf][kw - 1][m * 8 + jj * 4 + rr][lane] = acc[m][jj][rr];
  }
  __syncthreads();
  if (kw == 0) {
    #pragma unroll
    for (int m = 0; m < 4; ++m)
      #pragma unroll
      for (int jj = 0; jj < 2; ++jj)
        #pragma unroll
        for (int rr = 0; rr < 4; ++rr) {
          int ri = m * 8 + jj * 4 + rr;
          acc[m][jj][rr] += red[rhalf][0][ri][lane] + red[rhalf][1][ri][lane] + red[rhalf][2][ri][lane];
        }
  }
  if (w == 4) {
    #pragma unroll
    for (int m = 0; m < 4; ++m)
      #pragma unroll
      for (int jj = 0; jj < 2; ++jj)
        #pragma unroll
        for (int rr = 0; rr < 4; ++rr)
          red[1][0][m * 8 + jj * 4 + rr][lane] = acc[m][jj][rr];
  }
  __syncthreads();
  if (w == 0) {
    #pragma unroll
    for (int m = 0; m < 4; ++m)
      #pragma unroll
      for (int jj = 0; jj < 2; ++jj)
        #pragma unroll
        for (int rr = 0; rr < 4; ++rr) {
          float v = fmaxf(acc[m][jj][rr], red[1][0][m * 8 + jj * 4 + rr][lane]);
          int d = m * 16 + quad * 4 + rr;
          int p = p0 + jj * 16 + col;
          out[((size_t)d * V + p) * 6 + j] = v;
        }
  }
}

// ---------- host ----------
extern "C" void kernel_launch(void* const* d_in, const int* in_sizes, int n_in,
                              void* d_out, int out_size, void* d_ws, size_t ws_size,
                              hipStream_t stream) {
  const int* nbi = (const int*)d_in[0];
  const float* verts = (const float*)d_in[1];
  const float* fm = (const float*)d_in[2];
  const float* Wdim = (const float*)d_in[3];
  const float* W = (const float*)d_in[4];
  const float* Wdir = (const float*)d_in[5];
  float* out = (float*)d_out;
  float* ws = (float*)d_ws;
  int V = in_sizes[0] / NN;   // 2048

  unsigned short* A_bf  = (unsigned short*)ws;             // 221184 ush
  unsigned short* W2k   = (unsigned short*)(ws + 110592);  // 1769472 ush
  unsigned short* Wck   = (unsigned short*)(ws + 995328);  // 147456 ush
  unsigned short* fmTbf = (unsigned short*)(ws + 1069056); // 192*V ush
  size_t o = 1069056 + (size_t)96 * V;
  unsigned short* nfm = (unsigned short*)(ws + o);         // 27648*V ush [pg=p/2][1152][48]
  o += (size_t)13824 * V;
  unsigned short* wdB = (unsigned short*)(ws + o);         // 1024 ush

  int n0 = 2138112 + 192 * V + 1024;
  k0_expand<<<(n0 + 255) / 256, 256, 0, stream>>>(W, Wdir, fm, Wdim, A_bf, W2k, Wck, fmTbf,
                                                  wdB, out + (size_t)DO * V * 6, V);
  k12_main<<<V / 2, 256, 0, stream>>>(nbi, verts, fm, Wdim, wdB, A_bf, nfm, V);
  k3_feat<<<dim3(V / 32, 6), 512, 0, stream>>>(W2k, Wck, fmTbf, nfm, out, V);
}

// Round 11
// 157.088 us; speedup vs baseline: 1.2169x; 1.0061x over previous
//
#include <hip/hip_runtime.h>
#include <cstdint>
#include <cstddef>

#define NN 16   // neighbors
#define DI 32
#define DO 64

typedef short bf16x8 __attribute__((ext_vector_type(8)));
typedef short bf16x4 __attribute__((ext_vector_type(4)));
typedef float f32x4 __attribute__((ext_vector_type(4)));

#if defined(__has_builtin)
#  if __has_builtin(__builtin_amdgcn_mfma_f32_16x16x16_bf16)
#    define MFMA_K16(a, b, c) __builtin_amdgcn_mfma_f32_16x16x16_bf16(a, b, c, 0, 0, 0)
#    define HAVE_K16 1
#  elif __has_builtin(__builtin_amdgcn_mfma_f32_16x16x16bf16_1k)
#    define MFMA_K16(a, b, c) __builtin_amdgcn_mfma_f32_16x16x16bf16_1k(a, b, c, 0, 0, 0)
#    define HAVE_K16 1
#  endif
#  if __has_builtin(__builtin_amdgcn_cvt_pk_bf16_f32)
#    define HAVE_PKBF 1
#  endif
#endif

// ---------- tables ----------
__device__ __constant__ int c_INV[12][6] = {
  {0,1,2,3,4,5},{0,5,4,3,2,1},{4,3,0,5,2,1},{1,2,4,3,5,0},
  {3,5,2,0,4,1},{1,4,3,5,0,2},{4,0,3,1,2,5},{1,0,2,4,3,5},
  {4,1,2,5,0,3},{3,1,4,0,2,5},{2,1,4,5,3,0},{4,5,0,3,1,2}};
__device__ __constant__ int c_ROLL[5][6] = {
  {0,1,2,3,4,5},{0,2,3,4,5,1},{0,3,4,5,1,2},{0,4,5,1,2,3},{0,5,1,2,3,4}};
__device__ __constant__ float c_VS[12][3] = {
  {0.f, 0.5257311121f, 0.8506508084f},
  {0.f, 0.5257311121f, -0.8506508084f},
  {0.f, -0.5257311121f, 0.8506508084f},
  {0.f, -0.5257311121f, -0.8506508084f},
  {0.5257311121f, 0.8506508084f, 0.f},
  {0.5257311121f, -0.8506508084f, 0.f},
  {-0.5257311121f, 0.8506508084f, 0.f},
  {-0.5257311121f, -0.8506508084f, 0.f},
  {0.8506508084f, 0.f, 0.5257311121f},
  {0.8506508084f, 0.f, -0.5257311121f},
  {-0.8506508084f, 0.f, 0.5257311121f},
  {-0.8506508084f, 0.f, -0.5257311121f}};
__device__ __constant__ int c_C2V[6][2] = {{0,1},{6,7},{2,11},{4,9},{5,8},{3,10}};

// ---------- helpers ----------
__device__ inline unsigned short f2bf(float f) {
  unsigned int u = __float_as_uint(f);
  unsigned int r = (u + 0x7fffu + ((u >> 16) & 1u)) >> 16;   // RNE
  return (unsigned short)r;
}
__device__ inline unsigned int pk2(float a, float b) {
#ifdef HAVE_PKBF
  typedef __bf16 bf16v2 __attribute__((ext_vector_type(2)));
  union { bf16v2 v; unsigned int u; } cv;
  cv.v = __builtin_amdgcn_cvt_pk_bf16_f32(a, b);
  return cv.u;
#else
  return (unsigned int)f2bf(a) | ((unsigned int)f2bf(b) << 16);
#endif
}
__device__ inline unsigned short f2bf_fast(float a) {
  return (unsigned short)(pk2(a, a) & 0xffffu);
}

__device__ inline float sym13(const float* __restrict__ w, int k, int j) {
  if (k == 0)  return w[j == 0 ? 0 : 1];
  if (k == 1)  return w[j == 0 ? 2 : 3];
  if (k == 12) return w[j == 0 ? 4 : 5];
  int a = (k - 2) / 5, rr = (k - 2) % 5;
  return w[6 + a * 6 + c_ROLL[rr][j]];
}

// ---------- k0: weight expansion (k-major bf16) + fmT + wdB frags + passthrough ----------
__global__ __launch_bounds__(256) void k0_expand(
    const float* __restrict__ W, const float* __restrict__ Wdir,
    const float* __restrict__ fm, const float* __restrict__ Wdim,
    unsigned short* __restrict__ A_bf,
    unsigned short* __restrict__ W2k,
    unsigned short* __restrict__ Wck,
    unsigned short* __restrict__ fmTbf,   // [V][192] bf16
    unsigned short* __restrict__ wdB,     // 1024: B-frags of W_dim rows 0..31
    float* __restrict__ out_fm, int V) {
  int idx = blockIdx.x * 256 + threadIdx.x;
  if (idx < 221184) {
    int row = idx / 192, ci = idx % 192;
    int h = row / 144, k = (row / 12) % 12, r = row % 12;
    int c = ci / 6, i = ci % 6;
    int rt = row >> 4, rl = row & 15;
    int ks = ci >> 5, q = (ci >> 3) & 3, j = ci & 7;
    A_bf[(((rt * 6 + ks) * 4 + q) * 16 + rl) * 8 + j] =
        f2bf_fast(0.5f * sym13(&Wdir[(h * 32 + c) * 18], k, c_INV[r][i]));
  } else if (idx < 1990656) {
    int e = idx - 221184;
    int kr = e / 12288, rem = e % 12288;
    int k = kr / 12, r = kr % 12, d = rem / 192, ci = rem % 192;
    int c = ci / 6, i = ci % 6;
    int ks = ci >> 5, q = (ci >> 3) & 3, j = ci & 7;
    W2k[kr * 12288 + ((ks * 4 + q) * 64 + d) * 8 + j] =
        f2bf_fast(sym13(&W[(d * 32 + c) * 18], k, c_INV[r][i]));
  } else if (idx < 2138112) {
    int e = idx - 1990656;
    int r = e / 12288, rem = e % 12288, d = rem / 192, ci = rem % 192;
    int c = ci / 6, i = ci % 6;
    int ks = ci >> 5, q = (ci >> 3) & 3, j = ci & 7;
    Wck[r * 12288 + ((ks * 4 + q) * 64 + d) * 8 + j] =
        f2bf_fast(sym13(&W[(d * 32 + c) * 18], 12, c_INV[r][i]));
  } else if (idx < 2138112 + 192 * V) {
    int e = idx - 2138112;
    int p = e / 192, ci = e % 192, c = ci / 6, i = ci % 6;
    float v = fm[(c * V + p) * 6 + i];
    fmTbf[e] = f2bf_fast(v);
    out_fm[(c * V + p) * 6 + i] = v;
  } else {
    int e = idx - (2138112 + 192 * V);
    if (e < 1024) {
      int j = e & 7, lane = (e >> 3) & 63, ot = e >> 9;
      int k = ((lane >> 4) & 3) * 8 + j;
      int o = ot * 16 + (lane & 15);
      wdB[e] = f2bf_fast(Wdim[k * 32 + o]);
    }
  }
}

// ---------- k12: fused cross (W_dim MFMA) + act GEMM + softmax + nfm ----------
// 2 vertices/block, 256 threads (4 waves), grid V/2 = 1024.
// Phase C split across all 4 waves: wave w -> vertex w&1, mt (w>>1)*3..+2.
// Softmax without max-subtraction (logits bounded ~5 << 88); A-frag prefetch.
__global__ __launch_bounds__(256, 4) void k12_main(
    const int* __restrict__ nbi, const float* __restrict__ verts,
    const float* __restrict__ fm, const float* __restrict__ Wdim,
    const unsigned short* __restrict__ wdB,
    const unsigned short* __restrict__ A_bf,
    unsigned short* __restrict__ nfm, int V) {
  __shared__ __align__(16) unsigned short in_bf[2][96][40];  // 15360 B
  __shared__ __align__(16) float de_s[2][96];                // 768 B
  __shared__ __align__(16) unsigned short crossL[2][192][20];// 15360 B
  int t = threadIdx.x;
  int w = t >> 6, lane = t & 63;
  int quad = lane >> 4, col = lane & 15;
  int p0 = blockIdx.x * 2;
  int v = w & 1, hf = w >> 1;
  int p = p0 + v;

  // ---- phase G: gather ----
  for (int i = lane; i < 256; i += 64) {
    int n = i >> 4, c = hf * 16 + (i & 15);
    int nb = nbi[p * 16 + n];
    const float* src = fm + ((size_t)c * V + nb) * 6;
    float2 a  = *(const float2*)(src + 0);
    float2 b  = *(const float2*)(src + 2);
    float2 cd = *(const float2*)(src + 4);
    unsigned short* dst = &in_bf[v][n * 6][c];
    dst[0 * 40] = f2bf_fast(a.x);
    dst[1 * 40] = f2bf_fast(a.y);
    dst[2 * 40] = f2bf_fast(b.x);
    dst[3 * 40] = f2bf_fast(b.y);
    dst[4 * 40] = f2bf_fast(cd.x);
    dst[5 * 40] = f2bf_fast(cd.y);
  }
  if (hf == 0 && lane < 16) {
    int n = lane, nb = nbi[p * 16 + n];
    float px = verts[p * 3 + 0], py = verts[p * 3 + 1], pz = verts[p * 3 + 2];
    float qx = verts[nb * 3 + 0] - px, qy = verts[nb * 3 + 1] - py, qz = verts[nb * 3 + 2] - pz;
    float L = sqrtf(qx * qx + qy * qy + qz * qz);
    float inv = 1.0f / fmaxf(L, 1e-12f);
    qx *= inv; qy *= inv; qz *= inv;
    float de[12];
    #pragma unroll
    for (int vv = 0; vv < 12; ++vv)
      de[vv] = c_VS[vv][0] * qx + c_VS[vv][1] * qy + c_VS[vv][2] * qz;
    #pragma unroll
    for (int j = 0; j < 6; ++j)
      de_s[v][n * 6 + j] = fmaxf(de[c_C2V[j][0]], de[c_C2V[j][1]]);
  }
  __syncthreads();

  // ---- phase C: cross MFMA, all 4 waves (wave -> vertex w&1, 3 mt each) ----
  {
    int vv = w & 1;
    int mtb = (w >> 1) * 3;
    bf16x8 Bf[2];
    #pragma unroll
    for (int ot = 0; ot < 2; ++ot)
      Bf[ot] = *(const bf16x8*)(wdB + (size_t)(ot * 64 + lane) * 8);
    float wd32[2] = {Wdim[1024 + col], Wdim[1024 + 16 + col]};
    #pragma unroll
    for (int mi = 0; mi < 3; ++mi) {
      int mt = mtb + mi;
      bf16x8 a0 = *(const bf16x8*)&in_bf[vv][mt * 16 + col][quad * 8];
      f32x4 du = *(const f32x4*)&de_s[vv][mt * 16 + quad * 4];
      #pragma unroll
      for (int ot = 0; ot < 2; ++ot) {
        f32x4 acc = (f32x4){0.f, 0.f, 0.f, 0.f};
        acc = __builtin_amdgcn_mfma_f32_16x16x32_bf16(a0, Bf[ot], acc, 0, 0, 0);
        #pragma unroll
        for (int r = 0; r < 4; ++r)
          acc[r] = fmaf(du[r], wd32[ot], acc[r]);
        #pragma unroll
        for (int r = 0; r < 4; ++r) {
          int m = mt * 16 + quad * 4 + r;
          int n = m / 6, i = m - n * 6;
          crossL[vv][(ot * 16 + col) * 6 + i][n] = f2bf_fast(acc[r]);
        }
      }
    }
  }
  __syncthreads();

  // ---- build Afr from crossL (transpose reads, one-time) ----
  bf16x8 Afr[2][6];
  #pragma unroll
  for (int pi = 0; pi < 2; ++pi) {
    #pragma unroll
    for (int ks = 0; ks < 6; ++ks) {
      union { unsigned short s[8]; bf16x8 v8; } u;
      #pragma unroll
      for (int j = 0; j < 8; ++j)
        u.s[j] = crossL[pi][ks * 32 + quad * 8 + j][col];
      Afr[pi][ks] = u.v8;
    }
  }

  // ---- phase T: 18 tile iterations per wave, barrier-free, prefetched ----
  bf16x8 wf[6];
  {
    const unsigned short* Abase = A_bf + w * 3072 + quad * 128 + col * 8;
    #pragma unroll
    for (int ks = 0; ks < 6; ++ks) wf[ks] = *(const bf16x8*)(Abase + ks * 512);
  }
  for (int rt = w; rt < 72; rt += 4) {
    int h = rt / 9;
    f32x4 acc[2];
    acc[0] = (f32x4){0.f, 0.f, 0.f, 0.f};
    acc[1] = (f32x4){0.f, 0.f, 0.f, 0.f};
    #pragma unroll
    for (int ks = 0; ks < 6; ++ks) {
      acc[0] = __builtin_amdgcn_mfma_f32_16x16x32_bf16(Afr[0][ks], wf[ks], acc[0], 0, 0, 0);
      acc[1] = __builtin_amdgcn_mfma_f32_16x16x32_bf16(Afr[1][ks], wf[ks], acc[1], 0, 0, 0);
    }
    // prefetch next tile's A fragments (clamped; unused garbage on last iter)
    bf16x8 wfn[6];
    {
      int rtn = min(rt + 4, 71);
      const unsigned short* AbaseN = A_bf + rtn * 3072 + quad * 128 + col * 8;
      #pragma unroll
      for (int ks = 0; ks < 6; ++ks) wfn[ks] = *(const bf16x8*)(AbaseN + ks * 512);
    }
    int row0 = h * 24 + col;
    int row1 = min(h * 24 + 16 + col, 191);
    #pragma unroll
    for (int pi = 0; pi < 2; ++pi) {
      // ---- softmax over n (no max-subtraction; logits bounded) ----
      float e0 = __expf(acc[pi][0]), e1 = __expf(acc[pi][1]);
      float e2 = __expf(acc[pi][2]), e3 = __expf(acc[pi][3]);
      float s = (e0 + e1) + (e2 + e3);
      s += __shfl_xor(s, 16);
      s += __shfl_xor(s, 32);
      float inv = __builtin_amdgcn_rcpf(s);
      unsigned int lo = pk2(e0 * inv, e1 * inv);
      unsigned int hi = pk2(e2 * inv, e3 * inv);
      f32x4 o0 = (f32x4){0.f, 0.f, 0.f, 0.f}, o1 = o0;
#ifdef HAVE_K16
      union { uint2 u; bf16x4 v4; } bcvt;
      bcvt.u = make_uint2(lo, hi);
      bf16x4 a0 = *(const bf16x4*)&crossL[pi][row0][quad * 4];
      bf16x4 a1 = *(const bf16x4*)&crossL[pi][row1][quad * 4];
      o0 = MFMA_K16(a0, bcvt.v4, o0);
      o1 = MFMA_K16(a1, bcvt.v4, o1);
#else
      int s0l = quad * 32 + col, s1l = s0l + 16;
      unsigned int b0 = (unsigned int)__shfl((int)lo, s0l);
      unsigned int b1 = (unsigned int)__shfl((int)hi, s0l);
      unsigned int b2 = (unsigned int)__shfl((int)lo, s1l);
      unsigned int b3 = (unsigned int)__shfl((int)hi, s1l);
      bool vq = (quad < 2);
      union { uint4 u; bf16x8 v8; } cvt;
      cvt.u = make_uint4(vq ? b0 : 0u, vq ? b1 : 0u, vq ? b2 : 0u, vq ? b3 : 0u);
      union { unsigned short sv[8]; bf16x8 v8; } ua0, ua1;
      #pragma unroll
      for (int j = 0; j < 8; ++j) {
        int nn = quad * 8 + j;
        ua0.sv[j] = (nn < 16) ? crossL[pi][row0][nn] : (unsigned short)0;
        ua1.sv[j] = (nn < 16) ? crossL[pi][row1][nn] : (unsigned short)0;
      }
      o0 = __builtin_amdgcn_mfma_f32_16x16x32_bf16(ua0.v8, cvt.v8, o0, 0, 0, 0);
      o1 = __builtin_amdgcn_mfma_f32_16x16x32_bf16(ua1.v8, cvt.v8, o1, 0, 0, 0);
#endif
      size_t rowbase = (size_t)blockIdx.x * 55296 + (size_t)(rt * 16 + col) * 48 + pi * 24;
      uint2 w0;
      w0.x = pk2(o0[0], o0[1]);
      w0.y = pk2(o0[2], o0[3]);
      *(uint2*)(nfm + rowbase + quad * 4) = w0;
      if (quad < 2) {
        uint2 w1;
        w1.x = pk2(o1[0], o1[1]);
        w1.y = pk2(o1[2], o1[3]);
        *(uint2*)(nfm + rowbase + 16 + quad * 4) = w1;
      }
    }
    #pragma unroll
    for (int ks = 0; ks < 6; ++ks) wf[ks] = wfn[ks];
  }
}

// ---------- k3: MFMA feat GEMMs + center + fused c2v max -> out ----------
// 16 p per block, grid (V/16, 6) = 768 -> exactly 3 blocks/CU, 24 waves/CU.
// waves 0-3: r0 = c2v[j][0] (K-split 4); waves 4-7: r1. nfm [pg=p/2][1152][48].
__global__ __launch_bounds__(512) void k3_feat(
    const unsigned short* __restrict__ W2k,
    const unsigned short* __restrict__ Wck,
    const unsigned short* __restrict__ fmTbf,
    const unsigned short* __restrict__ nfm,
    float* __restrict__ out, int V) {
  __shared__ float red[2][3][16][64];   // 24576 B
  int pb = blockIdx.x, j = blockIdx.y;
  int t = threadIdx.x, w = t >> 6, lane = t & 63;
  int rhalf = w >> 2, kw = w & 3;
  int r = c_C2V[j][rhalf];
  int quad = lane >> 4, col = lane & 15;
  int p0 = pb * 16;
  f32x4 acc[4];
  #pragma unroll
  for (int m = 0; m < 4; ++m) acc[m] = (f32x4){0.f, 0.f, 0.f, 0.f};

  int base24[6];
  #pragma unroll
  for (int ks = 0; ks < 6; ++ks) {
    int ci = ks * 32 + quad * 8;
    int hh = ci / 24, oo = ci - hh * 24;
    base24[ks] = hh * 6912 + oo;   // hh*144*48 + oo
  }

  int pA = p0 + col;
  const unsigned short* Bn0 = nfm + (size_t)(pA >> 1) * 55296 + (pA & 1) * 24;
  const unsigned short* Bc0 = fmTbf + (size_t)pA * 192;

  int nkb = (kw == 3) ? 4 : 3;
  for (int i = 0; i < nkb; ++i) {
    int kb = kw * 3 + i;   // kw=3,i=3 -> 12 (center)
    const unsigned short* Ab;
    int kr48 = 0;
    if (kb < 12) { Ab = W2k + (size_t)(kb * 12 + r) * 12288; kr48 = (kb * 12 + r) * 48; }
    else         { Ab = Wck + (size_t)r * 12288; }
    const unsigned short* Albase = Ab + quad * 512 + col * 8;
    #pragma unroll
    for (int ks = 0; ks < 6; ++ks) {
      bf16x8 b0;
      if (kb < 12) {
        b0 = *(const bf16x8*)(Bn0 + base24[ks] + kr48);
      } else {
        b0 = *(const bf16x8*)(Bc0 + ks * 32 + quad * 8);
      }
      #pragma unroll
      for (int m = 0; m < 4; ++m) {
        bf16x8 a = *(const bf16x8*)(Albase + ks * 2048 + m * 128);
        acc[m] = __builtin_amdgcn_mfma_f32_16x16x32_bf16(a, b0, acc[m], 0, 0, 0);
      }
    }
  }
  if (kw > 0) {
    #pragma unroll
    for (int m = 0; m < 4; ++m)
      #pragma unroll
      for (int rr = 0; rr < 4; ++rr)
        red[rhalf][kw - 1][m * 4 + rr][lane] = acc[m][rr];
  }
  __syncthreads();
  if (kw == 0) {
    #pragma unroll
    for (int m = 0; m < 4; ++m)
      #pragma unroll
      for (int rr = 0; rr < 4; ++rr) {
        int ri = m * 4 + rr;
        acc[m][rr] += red[rhalf][0][ri][lane] + red[rhalf][1][ri][lane] + red[rhalf][2][ri][lane];
      }
  }
  if (w == 4) {
    #pragma unroll
    for (int m = 0; m < 4; ++m)
      #pragma unroll
      for (int rr = 0; rr < 4; ++rr)
        red[1][0][m * 4 + rr][lane] = acc[m][rr];
  }
  __syncthreads();
  if (w == 0) {
    #pragma unroll
    for (int m = 0; m < 4; ++m)
      #pragma unroll
      for (int rr = 0; rr < 4; ++rr) {
        float vmax = fmaxf(acc[m][rr], red[1][0][m * 4 + rr][lane]);
        int d = m * 16 + quad * 4 + rr;
        out[((size_t)d * V + p0 + col) * 6 + j] = vmax;
      }
  }
}

// ---------- host ----------
extern "C" void kernel_launch(void* const* d_in, const int* in_sizes, int n_in,
                              void* d_out, int out_size, void* d_ws, size_t ws_size,
                              hipStream_t stream) {
  const int* nbi = (const int*)d_in[0];
  const float* verts = (const float*)d_in[1];
  const float* fm = (const float*)d_in[2];
  const float* Wdim = (const float*)d_in[3];
  const float* W = (const float*)d_in[4];
  const float* Wdir = (const float*)d_in[5];
  float* out = (float*)d_out;
  float* ws = (float*)d_ws;
  int V = in_sizes[0] / NN;   // 2048

  unsigned short* A_bf  = (unsigned short*)ws;             // 221184 ush
  unsigned short* W2k   = (unsigned short*)(ws + 110592);  // 1769472 ush
  unsigned short* Wck   = (unsigned short*)(ws + 995328);  // 147456 ush
  unsigned short* fmTbf = (unsigned short*)(ws + 1069056); // 192*V ush
  size_t o = 1069056 + (size_t)96 * V;
  unsigned short* nfm = (unsigned short*)(ws + o);         // 27648*V ush [pg=p/2][1152][48]
  o += (size_t)13824 * V;
  unsigned short* wdB = (unsigned short*)(ws + o);         // 1024 ush

  int n0 = 2138112 + 192 * V + 1024;
  k0_expand<<<(n0 + 255) / 256, 256, 0, stream>>>(W, Wdir, fm, Wdim, A_bf, W2k, Wck, fmTbf,
                                                  wdB, out + (size_t)DO * V * 6, V);
  k12_main<<<V / 2, 256, 0, stream>>>(nbi, verts, fm, Wdim, wdB, A_bf, nfm, V);
  k3_feat<<<dim3(V / 16, 6), 512, 0, stream>>>(W2k, Wck, fmTbf, nfm, out, V);
}